// Round 6
// baseline (8061.298 us; speedup 1.0000x reference)
//
#include <hip/hip_runtime.h>

// ---------------------------------------------------------------------------
// Decoder_60868276519063: attention-LSTM decoder forward (loss, acc)
// B=32 T=800 E=512 D=1024 V=5000 L=149 (150 steps) A=512
// Round 6: NO grid barriers. Pure dataflow sync via step-tagged data words
// (fp8|tag8 u16 for z0/z1; bf16|tag16 u32 for q/hh1/g0) + cumulative
// counters for the atomicAdd attention combine. LDS-resident attention,
// fp8 MFMA GEMVs with register-resident weights (as r5).
// ---------------------------------------------------------------------------

typedef unsigned short u16;
typedef unsigned char u8;
typedef unsigned int u32;
typedef long long i64;
typedef unsigned long long u64;
typedef float f32x4 __attribute__((ext_vector_type(4)));
typedef float f32x2 __attribute__((ext_vector_type(2)));
typedef short s16x8 __attribute__((ext_vector_type(8)));

constexpr int cB = 32, cT = 800, cE = 512, cD = 1024, cV = 5000, cL = 149,
              cNS = 150, cA = 512;
constexpr int SOS = 1, EOS = 2;
constexpr int NBLK = 256;
constexpr float DS = 1.0f / 128.0f;   // fp8 descale: W x16, x x8

__device__ __forceinline__ float bf2f(u16 x){
  union { u32 u; float f; } v; v.u = ((u32)x) << 16; return v.f;
}
__device__ __forceinline__ u16 f2bf(float f){
  union { float f; u32 u; } v; v.f = f;
  u32 r = v.u + 0x7FFFu + ((v.u >> 16) & 1u);
  return (u16)(r >> 16);
}
__device__ __forceinline__ float frcp(float x){ return __builtin_amdgcn_rcpf(x); }
__device__ __forceinline__ float fsigm(float x){ return frcp(1.f + __expf(-x)); }
__device__ __forceinline__ float ftanh(float x){
  float u = __expf(2.f * x);
  return 1.f - 2.f * frcp(u + 1.f);
}
__device__ __forceinline__ f32x4 MFMA(s16x8 a, s16x8 b, f32x4 c){
  return __builtin_amdgcn_mfma_f32_16x16x32_bf16(a, b, c, 0, 0, 0);
}
__device__ __forceinline__ f32x4 MFMA8(i64 a, i64 b, f32x4 c){
  return __builtin_amdgcn_mfma_f32_16x16x32_fp8_fp8(a, b, c, 0, 0, 0);
}
__device__ __forceinline__ s16x8 LD8(const u16* p){ return *(const s16x8*)p; }
__device__ __forceinline__ u8 f2fp8(float x){
  return (u8)(__builtin_amdgcn_cvt_pk_fp8_f32(x, x, 0, false) & 0xFF);
}
__device__ __forceinline__ u32 pk4(float a, float b, float c, float d){
  u32 w = (u32)__builtin_amdgcn_cvt_pk_fp8_f32(a, b, 0, false);
  w = (u32)__builtin_amdgcn_cvt_pk_fp8_f32(c, d, (int)w, true);
  return w;
}
__device__ __forceinline__ void unpack8(u32 lo, u32 hi, float* o){
  f32x2 a = __builtin_amdgcn_cvt_pk_f32_fp8((int)lo, false);
  f32x2 b = __builtin_amdgcn_cvt_pk_f32_fp8((int)lo, true);
  f32x2 c = __builtin_amdgcn_cvt_pk_f32_fp8((int)hi, false);
  f32x2 d = __builtin_amdgcn_cvt_pk_f32_fp8((int)hi, true);
  o[0]=a[0]; o[1]=a[1]; o[2]=b[0]; o[3]=b[1];
  o[4]=c[0]; o[5]=c[1]; o[6]=d[0]; o[7]=d[1];
}

// ---- agent-scope (sc1) relaxed accessors (coherent at L3, no fences) ------
__device__ __forceinline__ float ld_sc(const float* p){
  return __hip_atomic_load(p, __ATOMIC_RELAXED, __HIP_MEMORY_SCOPE_AGENT);
}
__device__ __forceinline__ void st_sc(float* p, float v){
  __hip_atomic_store(p, v, __ATOMIC_RELAXED, __HIP_MEMORY_SCOPE_AGENT);
}
__device__ __forceinline__ u64 ld_sc8(const void* p){
  return __hip_atomic_load((const u64*)p, __ATOMIC_RELAXED, __HIP_MEMORY_SCOPE_AGENT);
}
__device__ __forceinline__ void st_sc8(void* p, u64 v){
  __hip_atomic_store((u64*)p, v, __ATOMIC_RELAXED, __HIP_MEMORY_SCOPE_AGENT);
}
__device__ __forceinline__ u32 ld_su(const u32* p){
  return __hip_atomic_load(p, __ATOMIC_RELAXED, __HIP_MEMORY_SCOPE_AGENT);
}
__device__ __forceinline__ void st_su(u32* p, u32 v){
  __hip_atomic_store(p, v, __ATOMIC_RELAXED, __HIP_MEMORY_SCOPE_AGENT);
}
// 2-byte store, coherent (sc0 sc1): single inst -> naturally atomic
__device__ __forceinline__ void st_s16(u16* p, u32 v){
  asm volatile("global_store_short %0, %1, off sc0 sc1" :: "v"(p), "v"(v) : "memory");
}

// ------------------------------- prologue ----------------------------------
__global__ void k_init(u32* ctl, u32* qt, float* c0, float* c1, u16* z1t,
                       float* att_acc, float* att_l){
  int i = blockIdx.x * blockDim.x + threadIdx.x, n = gridDim.x * blockDim.x;
  for (int k = i; k < 64; k += n) ctl[k] = 0;
  for (int k = i; k < cB * cA; k += n) qt[k] = 0;
  for (int k = i; k < 2 * cB * cD; k += n){ c0[k] = 0.f; c1[k] = 0.f; }
  for (int k = i; k < cB * cD / 2; k += n) ((u32*)z1t)[k] = 0;
  for (int k = i; k < 2 * cB * cE; k += n) att_acc[k] = 0.f;
  for (int k = i; k < 2 * cB; k += n) att_l[k] = 0.f;
}

__global__ void k_cvt(const float* __restrict__ s, u16* __restrict__ d, int n4){
  int i = blockIdx.x * blockDim.x + threadIdx.x, st = gridDim.x * blockDim.x;
  for (int k = i; k < n4; k += st){
    float4 v = ((const float4*)s)[k];
    ushort4 o; o.x = f2bf(v.x); o.y = f2bf(v.y); o.z = f2bf(v.z); o.w = f2bf(v.w);
    ((ushort4*)d)[k] = o;
  }
}

// hpad -> fp8 h-half of interleaved ph8 rows: [grp*16+8 .. +15]
__global__ void k_cvt8I(const float* __restrict__ s, u8* __restrict__ d, int n){
  int i = blockIdx.x * blockDim.x + threadIdx.x, st = gridDim.x * blockDim.x;
  for (int k = i; k < n; k += st){
    int row = k >> 6, grp = k & 63;
    const float4* p = (const float4*)(s + (size_t)row * 512 + grp * 8);
    float4 v0 = p[0], v1 = p[1];
    u32 lo = pk4(v0.x, v0.y, v0.z, v0.w);
    u32 hi = pk4(v1.x, v1.y, v1.z, v1.w);
    *(uint2*)(d + (size_t)row * 1024 + grp * 16 + 8) = make_uint2(lo, hi);
  }
}

__global__ void k_slice(const float* __restrict__ s, u16* __restrict__ d, int n,
                        int cshift, int srcld, int coff){
  int i = blockIdx.x * blockDim.x + threadIdx.x, st = gridDim.x * blockDim.x;
  int cmask = (1 << cshift) - 1;
  for (int k = i; k < n; k += st){
    int r = k >> cshift, c = k & cmask;
    d[k] = f2bf(s[(size_t)r * srcld + coff + c]);
  }
}

__global__ void k_transp(const float* __restrict__ s, u16* __restrict__ d, int n,
                         int rshift, int csrc){
  int i = blockIdx.x * blockDim.x + threadIdx.x, st = gridDim.x * blockDim.x;
  int mask = (1 << rshift) - 1;
  for (int k = i; k < n; k += st){
    int dd = k & mask, a = k >> rshift;
    d[k] = f2bf(s[(size_t)dd * csrc + a]);
  }
}

__global__ void k_bias(const float* a, const float* b, float* o, int n){
  int i = blockIdx.x * blockDim.x + threadIdx.x, st = gridDim.x * blockDim.x;
  for (int k = i; k < n; k += st) o[k] = a[k] + b[k];
}

// fp8 weight convert, x16 scale, row-permuted: dst row R=j*32+jj, jj=g*8+c
__global__ void k_wf8perm(const float* __restrict__ s, u8* __restrict__ d,
                          int n4, int kshift, int srcld, int coff){
  int i = blockIdx.x * blockDim.x + threadIdx.x, st = gridDim.x * blockDim.x;
  int kmask = (1 << kshift) - 1;
  for (int k = i; k < n4; k += st){
    int flat = k * 4;
    int R = flat >> kshift, kk = flat & kmask;
    int j = R >> 5, jj = R & 31, g = jj >> 3, c = jj & 7;
    const float* p = s + (size_t)(g * 1024 + j * 8 + c) * srcld + coff + kk;
    ((u32*)d)[k] = pk4(p[0]*16.f, p[1]*16.f, p[2]*16.f, p[3]*16.f);
  }
}

__global__ void k_wf8(const float* __restrict__ s, u8* __restrict__ d, int n4){
  int i = blockIdx.x * blockDim.x + threadIdx.x, st = gridDim.x * blockDim.x;
  for (int k = i; k < n4; k += st){
    float4 v = ((const float4*)s)[k];
    ((u32*)d)[k] = pk4(v.x*16.f, v.y*16.f, v.z*16.f, v.w*16.f);
  }
}

// WdecT fp8: dst[a][dd] = Wdec[dd][a] * 16, dst [512][1024]
__global__ void k_wf8t(const float* __restrict__ s, u8* __restrict__ d, int n4){
  int i = blockIdx.x * blockDim.x + threadIdx.x, st = gridDim.x * blockDim.x;
  for (int k = i; k < n4; k += st){
    int flat = k * 4;
    int a = flat >> 10, dd = flat & 1023;
    ((u32*)d)[k] = pk4(s[(size_t)(dd+0)*512 + a]*16.f,
                       s[(size_t)(dd+1)*512 + a]*16.f,
                       s[(size_t)(dd+2)*512 + a]*16.f,
                       s[(size_t)(dd+3)*512 + a]*16.f);
  }
}

// ey[r][:] = embb[tok(r)][:]  (bf16 gather), r = s*32+b
__global__ void k_gather(const u16* __restrict__ embb, const int* __restrict__ ys,
                         u16* __restrict__ ey, int n16){
  int i = blockIdx.x * blockDim.x + threadIdx.x, st = gridDim.x * blockDim.x;
  for (int k = i; k < n16; k += st){
    int r = k >> 7, seg = k & 127;
    int s = r >> 5, b = r & 31;
    int tok = (s == 0) ? SOS : ys[b * cL + (s - 1)];
    ((uint4*)ey)[(size_t)r * 128 + seg] =
        ((const uint4*)embb)[(size_t)tok * 128 + seg];
  }
}

// pe GEMM: [25600x512] @ WencT[512 a][512 e]^T -> fp8 into ph8 pe-half
__global__ __launch_bounds__(512, 1) void k_pe2(const u16* __restrict__ A,
    const u16* __restrict__ Bw, u8* __restrict__ ph8){
  int tid = threadIdx.x, w = tid >> 6, l = tid & 63;
  int col = l & 15, kin = 8 * (l >> 4);
  int mw = w >> 2, nw = w & 3;
  int m0 = blockIdx.x * 128 + mw * 64;
  int n0 = nw * 128;
  f32x4 acc[4][8] = {};
  for (int kc = 0; kc < 16; ++kc){
    int k = kc * 32 + kin;
    s16x8 af[4], bf[8];
    #pragma unroll
    for (int i = 0; i < 4; ++i) af[i] = LD8(A + (size_t)(m0 + i*16 + col)*512 + k);
    #pragma unroll
    for (int j = 0; j < 8; ++j) bf[j] = LD8(Bw + (size_t)(n0 + j*16 + col)*512 + k);
    #pragma unroll
    for (int i = 0; i < 4; ++i)
      #pragma unroll
      for (int j = 0; j < 8; ++j) acc[i][j] = MFMA(af[i], bf[j], acc[i][j]);
  }
  int hi4 = (l >> 4) * 4;
  #pragma unroll
  for (int i = 0; i < 4; ++i)
    #pragma unroll
    for (int j = 0; j < 8; ++j){
      int a0 = n0 + j * 16 + col;
      size_t boff = ((size_t)(a0 >> 3) << 4) + (a0 & 7);
      #pragma unroll
      for (int r = 0; r < 4; ++r){
        int row = m0 + i * 16 + hi4 + r;
        ph8[(size_t)row * 1024 + boff] = f2fp8(acc[i][j][r]);
      }
    }
}

// eyproj GEMM: ey[4800x1024] @ Wih0m[4096x1024]^T + biases -> bf16 eyproj
// + tagged-u32 (tag 0) g0t for step 0
__global__ __launch_bounds__(512, 1) void k_ey2(const u16* __restrict__ ey,
    const u16* __restrict__ Wm, const float* __restrict__ bih0,
    const float* __restrict__ bhh0, u16* __restrict__ eyproj,
    u32* __restrict__ g0t){
  int tid = threadIdx.x, w = tid >> 6, l = tid & 63;
  int col = l & 15, kin = 8 * (l >> 4);
  int mw = w >> 2, nw = w & 3;
  int m0 = blockIdx.x * 128 + mw * 64;
  int n0 = blockIdx.y * 512 + nw * 128;
  f32x4 acc[4][8] = {};
  for (int kc = 0; kc < 32; ++kc){
    int k = kc * 32 + kin;
    s16x8 af[4], bf[8];
    #pragma unroll
    for (int i = 0; i < 4; ++i){
      int ar = m0 + i * 16 + col; ar = (ar < 4800) ? ar : 0;
      af[i] = LD8(ey + (size_t)ar * 1024 + k);
    }
    #pragma unroll
    for (int j = 0; j < 8; ++j) bf[j] = LD8(Wm + (size_t)(n0 + j*16 + col)*1024 + k);
    #pragma unroll
    for (int i = 0; i < 4; ++i)
      #pragma unroll
      for (int j = 0; j < 8; ++j) acc[i][j] = MFMA(af[i], bf[j], acc[i][j]);
  }
  int hi4 = (l >> 4) * 4;
  #pragma unroll
  for (int i = 0; i < 4; ++i)
    #pragma unroll
    for (int j = 0; j < 8; ++j){
      int jc = n0 + j * 16 + col;
      float bj = bih0[jc] + bhh0[jc];
      #pragma unroll
      for (int r = 0; r < 4; ++r){
        int row = m0 + i * 16 + hi4 + r;
        if (row < 4800){
          float val = acc[i][j][r] + bj;
          eyproj[(size_t)row * 4096 + jc] = f2bf(val);
          if (row < 32) g0t[(size_t)row * 4096 + jc] = (u32)f2bf(val); // tag 0
        }
      }
    }
}

// ------------------------------ main loop ----------------------------------
struct LoopArgs {
  const int* hlen;
  const u8* ph8;
  const u16* eyproj;
  const u8* Wapf8; const u8* Whh1f8; const u8* Wih1f8; const u8* Whh0f8;
  const u8* WdecTf8;
  const float* vatt; const float* bias01;
  u32* qt; float* att_acc; float* att_l;
  u32* g0t; u32* hh1t; u16* z0t; u16* z1t;
  float* c0; float* c1; u16* z1all;
  u32* ctl;   // [0..31]=acnt  [32+8p]=scnt  [48+8p]=zdone
};

constexpr int SPZ = 1048;   // LDS x row stride (bytes), K=1024
constexpr int SPA = 536;    // K=512

struct P1Lds { float red[8][512]; float ls[8]; };
struct GvLds { u8 x[32 * SPZ]; float acc[8][2][16][17]; };
union LoopLds { P1Lds p1; GvLds gv; };

// stage tagged z (u16 = fp8|tag8) -> fp8 LDS x; retries until all tags match
template<int SP>
__device__ __forceinline__ void stage_ztag(LoopLds& L, const u16* zt, int tid,
                                           int tag){
  int r = tid >> 4, cb = (tid & 15) * 64;
  const u16* src = zt + (size_t)r * 1024 + cb;
  const u64 tmask = 0xFF00FF00FF00FF00ULL;
  const u64 texp = 0x0100010001000100ULL * (u64)(tag & 0xFF);
  u64 v[16];
  for(;;){
    bool ok = true;
    #pragma unroll
    for (int i = 0; i < 16; ++i) v[i] = ld_sc8(src + i * 4);
    #pragma unroll
    for (int i = 0; i < 16; ++i) ok &= ((v[i] & tmask) == texp);
    if (__all(ok)) break;
    __builtin_amdgcn_s_sleep(1);
  }
  u64* dst = (u64*)&L.gv.x[r * SP + cb];
  #pragma unroll
  for (int i = 0; i < 8; ++i){
    u32 lo = __builtin_amdgcn_perm((u32)(v[2*i] >> 32),   (u32)v[2*i],   0x06040200u);
    u32 hi = __builtin_amdgcn_perm((u32)(v[2*i+1] >> 32), (u32)v[2*i+1], 0x06040200u);
    dst[i] = ((u64)hi << 32) | lo;
  }
}

// block GEMV from register-resident weights: wave w: nt = w/KH, kh = w%KH.
template<int KH, int ITERS, int SP>
__device__ __forceinline__ void gemv_reg(const i64* wreg, LoopLds& L, int tid){
  const int w = tid >> 6, l = tid & 63;
  const int col = l & 15, kin = 8 * (l >> 4);
  const int kh = (KH == 4) ? (w & 3) : (w & 1);
  constexpr int KB = ITERS * 32;
  const u8* xr = &L.gv.x[col * SP + kh * KB + kin];
  f32x4 a0 = {0.f,0.f,0.f,0.f}, a1 = {0.f,0.f,0.f,0.f};
  #pragma unroll
  for (int kc = 0; kc < ITERS; ++kc){
    i64 x0 = *(const i64*)(xr + kc * 32);
    i64 x1 = *(const i64*)(xr + 16 * SP + kc * 32);
    a0 = MFMA8(x0, wreg[kc], a0);
    a1 = MFMA8(x1, wreg[kc], a1);
  }
  const int hi4 = (l >> 4) * 4;
  #pragma unroll
  for (int r = 0; r < 4; ++r){
    L.gv.acc[w][0][hi4 + r][col] = a0[r];
    L.gv.acc[w][1][hi4 + r][col] = a1[r];
  }
}

__global__ __launch_bounds__(512, 1) void k_loop(LoopArgs g_){
  __shared__ __align__(16) LoopLds L;
  __shared__ __align__(16) u8 ph8_lds[100 * 1024];
  const int blk = blockIdx.x, tid = threadIdx.x;
  const int w = tid >> 6, l = tid & 63;
  const int col = l & 15, kin = 8 * (l >> 4);
  const int b_att = blk >> 3, oct = blk & 7;
  const int hl = g_.hlen[b_att];
  const int t0 = oct * 100;
  const int t1 = (t0 + 100 < hl) ? t0 + 100 : hl;
  const int nrow = t1 - t0;
  float vv[8];
  #pragma unroll
  for (int i = 0; i < 8; ++i) vv[i] = g_.vatt[l * 8 + i];
  for (int idx = tid; idx < nrow * 64; idx += 512){
    int rr = idx >> 6, gg = idx & 63;
    *(uint4*)&ph8_lds[rr * 1024 + gg * 16] =
        *(const uint4*)(g_.ph8 + ((size_t)b_att * cT + t0 + rr) * 1024 + gg * 16);
  }
  // ---- preload step-invariant weight fragments into registers (as r5) ----
  i64 wB[8], wC[16];
  {
    const int nt4 = w >> 2, kh4 = w & 3;
    const int nt2 = w >> 1, kh2 = w & 1;
    if (blk < 128){
      const u8* wr = g_.Wapf8 + (size_t)blk * 32 * 512 +
                     (size_t)(nt4 * 16 + col) * 512 + kh4 * 128 + kin;
      #pragma unroll
      for (int kc = 0; kc < 4; ++kc) wB[kc] = *(const i64*)(wr + kc * 32);
      const u8* wr2 = g_.Wih1f8 + (size_t)blk * 32 * 1024 +
                      (size_t)(nt4 * 16 + col) * 1024 + kh4 * 256 + kin;
      #pragma unroll
      for (int kc = 0; kc < 8; ++kc) wC[kc] = *(const i64*)(wr2 + kc * 32);
    } else {
      const u8* wr = g_.Whh1f8 + (size_t)(blk - 128) * 32 * 1024 +
                     (size_t)(nt4 * 16 + col) * 1024 + kh4 * 256 + kin;
      #pragma unroll
      for (int kc = 0; kc < 8; ++kc) wB[kc] = *(const i64*)(wr + kc * 32);
      if (blk < 192){
        const u8* wr2 = g_.Whh0f8 + (size_t)(blk - 128) * 64 * 1024 +
                        (size_t)(nt2 * 16 + col) * 1024 + kh2 * 512 + kin;
        #pragma unroll
        for (int kc = 0; kc < 16; ++kc) wC[kc] = *(const i64*)(wr2 + kc * 32);
      } else if (blk < 208){
        const u8* wr2 = g_.WdecTf8 + (size_t)(blk - 192) * 32 * 1024 +
                        (size_t)(nt4 * 16 + col) * 1024 + kh4 * 256 + kin;
        #pragma unroll
        for (int kc = 0; kc < 8; ++kc) wC[kc] = *(const i64*)(wr2 + kc * 32);
      }
    }
  }
  __syncthreads();

  for (int s = 0; s < cNS; ++s){
    const int p = s & 1;
    u64 eyw = 0;
    // ================= A: attention (tag-gated q) ========================
    {
      const u32* qrow = g_.qt + b_att * cA + l * 8;
      u64 qw[4];
      const u64 tmaskq = 0xFFFF0000FFFF0000ULL;
      const u64 texpq  = ((u64)(u32)s << 16) | ((u64)(u32)s << 48);
      for(;;){
        bool ok = true;
        #pragma unroll
        for (int i = 0; i < 4; ++i){
          qw[i] = ld_sc8(qrow + i * 2);
          ok &= ((qw[i] & tmaskq) == texpq);
        }
        if (__all(ok)) break;
        __builtin_amdgcn_s_sleep(1);
      }
      if (nrow > 0){
        float qv[8];
        #pragma unroll
        for (int i = 0; i < 4; ++i){
          qv[2*i]   = bf2f((u16)(qw[i] & 0xFFFF));
          qv[2*i+1] = bf2f((u16)((qw[i] >> 32) & 0xFFFF));
        }
        float acc8[8] = {0.f,0.f,0.f,0.f,0.f,0.f,0.f,0.f};
        float lsum = 0.f;
        for (int t = t0 + w; t < t1; t += 8){
          uint4 v = *(const uint4*)&ph8_lds[(t - t0) * 1024 + l * 16];
          float x[8]; unpack8(v.x, v.y, x);
          float e_ = 0.f;
          #pragma unroll
          for (int i = 0; i < 8; ++i) e_ += vv[i] * ftanh(x[i] + qv[i]);
          #pragma unroll
          for (int m = 1; m < 64; m <<= 1) e_ += __shfl_xor(e_, m, 64);
          float wt = __expf(e_);          // |e| <= sum|v_att| ~ 8.2
          lsum += wt;
          float h[8]; unpack8(v.z, v.w, h);
          #pragma unroll
          for (int i = 0; i < 8; ++i) acc8[i] = fmaf(wt, h[i], acc8[i]);
        }
        *(f32x4*)&L.p1.red[w][l * 8]     = *(f32x4*)&acc8[0];
        *(f32x4*)&L.p1.red[w][l * 8 + 4] = *(f32x4*)&acc8[4];
        if (l == 0) L.p1.ls[w] = lsum;
        __syncthreads();
        float vsum = 0.f;
        #pragma unroll
        for (int ww = 0; ww < 8; ++ww) vsum += L.p1.red[ww][tid];
        // zdone gate (parity buffer has been re-zeroed)
        if (tid == 0){
          while (ld_su(&g_.ctl[48 + 8*p]) < (u32)(s >> 1))
            __builtin_amdgcn_s_sleep(2);
        }
        __syncthreads();
        atomicAdd(&g_.att_acc[((size_t)p*cB + b_att)*cE + tid], vsum);
        if (tid == 0){
          float ls = 0.f;
          #pragma unroll
          for (int i = 0; i < 8; ++i) ls += L.p1.ls[i];
          atomicAdd(&g_.att_l[p*cB + b_att], ls);
        }
      }
      __syncthreads();   // drains all waves' adds before signaling
      if (tid == 0)
        __hip_atomic_fetch_add(&g_.ctl[b_att], 1u, __ATOMIC_RELAXED,
                               __HIP_MEMORY_SCOPE_AGENT);
    }
    // ================= B =================================================
    if (blk < 128){
      // acnt gate: all 256 blocks finished A(s)
      if (tid == 0){
        u32 tgt = 8u * (u32)(s + 1);
        for(;;){
          bool ok = true;
          #pragma unroll
          for (int i = 0; i < 16; ++i){
            u64 v = ld_sc8(&g_.ctl[i * 2]);
            ok &= ((u32)v >= tgt) && ((u32)(v >> 32) >= tgt);
          }
          if (ok) break;
          __builtin_amdgcn_s_sleep(2);
        }
      }
      __syncthreads();
      { // stage att_c (normalize, fp8) -> LDS
        int r = tid >> 4, cc = (tid & 15) * 32;
        const float* src = g_.att_acc + ((size_t)p*cB + r)*cE + cc;
        float lsm = ld_sc(g_.att_l + p*cB + r);
        u64 av[16];
        #pragma unroll
        for (int i = 0; i < 16; ++i) av[i] = ld_sc8(src + i*2);
        float sc = 8.0f / lsm;
        u32 wd[8];
        #pragma unroll
        for (int j = 0; j < 8; ++j){
          union { u64 q; float f[2]; } a, b;
          a.q = av[2*j]; b.q = av[2*j+1];
          wd[j] = pk4(a.f[0]*sc, a.f[1]*sc, b.f[0]*sc, b.f[1]*sc);
        }
        u64* dst = (u64*)&L.gv.x[r * SPA + cc];
        #pragma unroll
        for (int j = 0; j < 4; ++j) dst[j] = ((u64)wd[2*j+1] << 32) | wd[2*j];
      }
      __syncthreads();
      if (tid == 0)
        __hip_atomic_fetch_add(&g_.ctl[32 + 8*p], 1u, __ATOMIC_RELAXED,
                               __HIP_MEMORY_SCOPE_AGENT);
      // early g0 gate loads (hide under gemv)
      u32 gw[4]; bool gok = true;
      int bb = tid >> 3, dc = tid & 7, d = blk * 8 + dc;
      if (tid < 256){
        #pragma unroll
        for (int g = 0; g < 4; ++g){
          gw[g] = ld_su(&g_.g0t[(size_t)bb*4096 + g*1024 + d]);
          gok &= ((gw[g] >> 16) == (u32)s);
        }
      }
      gemv_reg<4, 4, SPA>(wB, L, tid);
      __syncthreads();
      if (tid < 256){
        if (!__all(gok)){
          for(;;){
            bool ok = true;
            #pragma unroll
            for (int g = 0; g < 4; ++g){
              gw[g] = ld_su(&g_.g0t[(size_t)bb*4096 + g*1024 + d]);
              ok &= ((gw[g] >> 16) == (u32)s);
            }
            if (__all(ok)) break;
            __builtin_amdgcn_s_sleep(1);
          }
        }
        int mt = bb >> 4, rr = bb & 15;
        float gate[4];
        #pragma unroll
        for (int g = 0; g < 4; ++g){
          int jj = g * 8 + dc;
          float v = 0.f;
          #pragma unroll
          for (int kh = 0; kh < 4; ++kh)
            v += L.gv.acc[(jj >> 4) * 4 + kh][mt][rr][jj & 15];
          gate[g] = v * DS + bf2f((u16)(gw[g] & 0xFFFF));
        }
        float c = fsigm(gate[1]) * g_.c0[(size_t)p*cB*cD + bb*cD + d] +
                  fsigm(gate[0]) * ftanh(gate[2]);
        float z = fsigm(gate[3]) * ftanh(c);
        g_.c0[(size_t)(p ^ 1)*cB*cD + bb*cD + d] = c;
        st_s16(&g_.z0t[bb * cD + d],
               (u32)(f2fp8(z * 8.f) | (((s + 1) & 0xFF) << 8)));
      }
    } else {
      // hh1 path (blocks 128-255), gated by z1 tags == s
      if (blk < 192 && s < cNS - 1){
        int b = tid >> 4, j4 = (tid & 15) * 4;
        eyw = *(const u64*)(g_.eyproj + (((size_t)(s+1)*cB + b)*4096) +
                            (blk - 128) * 64 + j4);
      }
      stage_ztag<SPZ>(L, g_.z1t, tid, s);
      __syncthreads();
      gemv_reg<4, 8, SPZ>(wB, L, tid);
      __syncthreads();
      {
        const int jb = (blk - 128) * 32;
        int b = tid >> 4, j2 = (tid & 15) * 2;
        int mt = b >> 4, rr = b & 15;
        u32 ow[2];
        #pragma unroll
        for (int k = 0; k < 2; ++k){
          int jj = j2 + k;
          float v = 0.f;
          #pragma unroll
          for (int kh = 0; kh < 4; ++kh)
            v += L.gv.acc[(jj >> 4)*4 + kh][mt][rr][jj & 15];
          ow[k] = ((u32)(s + 1) << 16) | f2bf(v * DS + g_.bias01[jb + jj]);
        }
        st_sc8(&g_.hh1t[(size_t)b*4096 + jb + j2], ((u64)ow[1] << 32) | ow[0]);
      }
    }
    // ================= C =================================================
    if (blk < 128){
      stage_ztag<SPZ>(L, g_.z0t, tid, s + 1);
      __syncthreads();
      // early hh1 gate loads (hide under gemv)
      u32 hw[4]; bool hok = true;
      int bb = tid >> 3, dc = tid & 7, d = blk * 8 + dc;
      if (tid < 256){
        #pragma unroll
        for (int g = 0; g < 4; ++g){
          hw[g] = ld_su(&g_.hh1t[(size_t)bb*4096 + g*1024 + d]);
          hok &= ((hw[g] >> 16) == (u32)(s + 1));
        }
      }
      gemv_reg<4, 8, SPZ>(wC, L, tid);
      __syncthreads();
      if (tid < 256){
        if (!__all(hok)){
          for(;;){
            bool ok = true;
            #pragma unroll
            for (int g = 0; g < 4; ++g){
              hw[g] = ld_su(&g_.hh1t[(size_t)bb*4096 + g*1024 + d]);
              ok &= ((hw[g] >> 16) == (u32)(s + 1));
            }
            if (__all(ok)) break;
            __builtin_amdgcn_s_sleep(1);
          }
        }
        int mt = bb >> 4, rr = bb & 15;
        float gate[4];
        #pragma unroll
        for (int g = 0; g < 4; ++g){
          int jj = g * 8 + dc;
          float v = 0.f;
          #pragma unroll
          for (int kh = 0; kh < 4; ++kh)
            v += L.gv.acc[(jj >> 4) * 4 + kh][mt][rr][jj & 15];
          gate[g] = v * DS + bf2f((u16)(hw[g] & 0xFFFF));
        }
        float c = fsigm(gate[1]) * g_.c1[(size_t)p*cB*cD + bb*cD + d] +
                  fsigm(gate[0]) * ftanh(gate[2]);
        float z = fsigm(gate[3]) * ftanh(c);
        g_.c1[(size_t)(p ^ 1)*cB*cD + bb*cD + d] = c;
        g_.z1all[((size_t)s + 1)*cB*cD + bb*cD + d] = f2bf(z);
        st_s16(&g_.z1t[bb * cD + d],
               (u32)(f2fp8(z * 8.f) | (((s + 1) & 0xFF) << 8)));
      }
    } else if (blk < 192){
      stage_ztag<SPZ>(L, g_.z0t, tid, s + 1);
      __syncthreads();
      gemv_reg<2, 16, SPZ>(wC, L, tid);
      __syncthreads();
      if (s < cNS - 1){
        const int jb = (blk - 128) * 64;
        int b = tid >> 4, j4 = (tid & 15) * 4;
        int mt = b >> 4, rr = b & 15;
        u32 ow[4];
        #pragma unroll
        for (int k = 0; k < 4; ++k){
          int jj = j4 + k;
          float v = 0.f;
          #pragma unroll
          for (int kh = 0; kh < 2; ++kh)
            v += L.gv.acc[(jj >> 4)*2 + kh][mt][rr][jj & 15];
          ow[k] = ((u32)(s + 1) << 16) |
                  f2bf(v * DS + bf2f(((const u16*)&eyw)[k]));
        }
        st_sc8(&g_.g0t[(size_t)b*4096 + jb + j4],     ((u64)ow[1] << 32) | ow[0]);
        st_sc8(&g_.g0t[(size_t)b*4096 + jb + j4 + 2], ((u64)ow[3] << 32) | ow[2]);
      }
    } else if (blk < 208){
      stage_ztag<SPZ>(L, g_.z0t, tid, s + 1);
      __syncthreads();
      gemv_reg<4, 8, SPZ>(wC, L, tid);
      __syncthreads();
      if (s < cNS - 1){
        const int jb = (blk - 192) * 32;
        int b = tid >> 4, j2 = (tid & 15) * 2;
        int mt = b >> 4, rr = b & 15;
        u32 ow[2];
        #pragma unroll
        for (int k = 0; k < 2; ++k){
          int jj = j2 + k;
          float v = 0.f;
          #pragma unroll
          for (int kh = 0; kh < 4; ++kh)
            v += L.gv.acc[(jj >> 4)*4 + kh][mt][rr][jj & 15];
          ow[k] = ((u32)(s + 1) << 16) | f2bf(v * DS);
        }
        st_sc8(&g_.qt[(size_t)b*cA + jb + j2], ((u64)ow[1] << 32) | ow[0]);
      }
    } else if (blk == 208){
      // zero parity buffer once all 128 staging blocks consumed it
      if (tid == 0){
        u32 tgt = 128u * ((u32)(s >> 1) + 1u);
        while (ld_su(&g_.ctl[32 + 8*p]) < tgt) __builtin_amdgcn_s_sleep(4);
      }
      __syncthreads();
      {
        float* aa = g_.att_acc + (size_t)p*cB*cE;
        for (int i = tid; i < cB*cE; i += 512) st_sc(&aa[i], 0.f);
        if (tid < cB) st_sc(&g_.att_l[p*cB + tid], 0.f);
      }
      __syncthreads();
      if (tid == 0) st_su(&g_.ctl[48 + 8*p], (u32)(s >> 1) + 1u);
    }
  }
}

// ------------------------------ epilogue -----------------------------------
__global__ __launch_bounds__(256) void k_ce1(const u16* __restrict__ z1all,
    const u16* __restrict__ Woutb, const float* __restrict__ bout,
    const int* __restrict__ ys, float* __restrict__ pmax, float* __restrict__ psum,
    int* __restrict__ pai, float* __restrict__ tgtl){
  int blk = blockIdx.x;
  int sc = blk / 40, vc = blk % 40;
  int tid = threadIdx.x, w = tid >> 6, l = tid & 63;
  int kin = 8 * (l >> 4), col = l & 15;
  int v0 = vc * 128 + w * 32;
  int vA = v0 + col, vB = v0 + 16 + col;
  float boA = (vA < cV) ? bout[vA] : 0.f;
  float boB = (vB < cV) ? bout[vB] : 0.f;
  const u16* wrA = Woutb + (size_t)((vA < cV) ? vA : cV - 1) * cD;
  const u16* wrB = Woutb + (size_t)((vB < cV) ? vB : cV - 1) * cD;
  __shared__ int tgt_sh[32];
  __shared__ float rsm[4][32], rss[4][32];
  __shared__ int rsi[4][32];
  for (int si = 0; si < 5; ++si){
    int s = sc * 5 + si;
    if (tid < 32) tgt_sh[tid] = (s < cL) ? ys[tid * cL + s] : EOS;
    __syncthreads();
    const u16* z1s = z1all + ((size_t)s + 1) * cB * cD;
    f32x4 aA0 = {0.f,0.f,0.f,0.f}, aA1 = {0.f,0.f,0.f,0.f};
    f32x4 aB0 = {0.f,0.f,0.f,0.f}, aB1 = {0.f,0.f,0.f,0.f};
    for (int kc = 0; kc < 32; ++kc){
      int k = kc * 32 + kin;
      s16x8 x0 = LD8(z1s + (size_t)col * cD + k);
      s16x8 x1 = LD8(z1s + (size_t)(16 + col) * cD + k);
      s16x8 bA = LD8(wrA + k);
      s16x8 bB = LD8(wrB + k);
      aA0 = MFMA(x0, bA, aA0); aA1 = MFMA(x1, bA, aA1);
      aB0 = MFMA(x0, bB, aB0); aB1 = MFMA(x1, bB, aB1);
    }
    #pragma unroll
    for (int mt = 0; mt < 2; ++mt)
    #pragma unroll
    for (int reg = 0; reg < 4; ++reg){
      int row = mt * 16 + (l >> 4) * 4 + reg;
      float va = (mt ? aA1[reg] : aA0[reg]) + boA; if (vA >= cV) va = -1e30f;
      float vb = (mt ? aB1[reg] : aB0[reg]) + boB; if (vB >= cV) vb = -1e30f;
      int tg = tgt_sh[row];
      if (vA == tg) tgtl[(size_t)s * cB + row] = va;
      if (vB == tg) tgtl[(size_t)s * cB + row] = vb;
      float mx = fmaxf(va, vb);
      int ix = (va >= vb) ? vA : vB;
      #pragma unroll
      for (int m = 1; m < 16; m <<= 1){
        float om = __shfl_xor(mx, m, 64);
        int oi = __shfl_xor(ix, m, 64);
        if (om > mx || (om == mx && oi < ix)){ mx = om; ix = oi; }
      }
      float se = __expf(va - mx) + __expf(vb - mx);
      #pragma unroll
      for (int m = 1; m < 16; m <<= 1) se += __shfl_xor(se, m, 64);
      if ((l & 15) == 0){ rsm[w][row] = mx; rss[w][row] = se; rsi[w][row] = ix; }
    }
    __syncthreads();
    if (tid < 32){
      int b = tid;
      float gm = -1e30f;
      #pragma unroll
      for (int w2 = 0; w2 < 4; ++w2) gm = fmaxf(gm, rsm[w2][b]);
      float gs = 0.f; float bv = -1e30f; int bix = 0x7fffffff;
      #pragma unroll
      for (int w2 = 0; w2 < 4; ++w2){
        gs += rss[w2][b] * __expf(rsm[w2][b] - gm);
        float v = rsm[w2][b]; int ii = rsi[w2][b];
        if (v > bv || (v == bv && ii < bix)){ bv = v; bix = ii; }
      }
      size_t o = ((size_t)s * cB + b) * 40 + vc;
      pmax[o] = gm; psum[o] = gs; pai[o] = bix;
    }
    __syncthreads();
  }
}

__global__ __launch_bounds__(64) void k_ce2(const float* __restrict__ pmax,
    const float* __restrict__ psum, const int* __restrict__ pai,
    const float* __restrict__ tgtl, const int* __restrict__ ys,
    float* __restrict__ cestep){
  int s = blockIdx.x, tid = threadIdx.x;
  float nll = 0.f, cor = 0.f;
  if (tid < 32){
    int b = tid;
    size_t o = ((size_t)s * cB + b) * 40;
    float gm = -1e30f;
    for (int c = 0; c < 40; ++c) gm = fmaxf(gm, pmax[o + c]);
    float gs = 0.f; float bv = -1e30f; int bix = 0x7fffffff;
    for (int c = 0; c < 40; ++c){
      gs += psum[o + c] * __expf(pmax[o + c] - gm);
      float v = pmax[o + c]; int ii = pai[o + c];
      if (v > bv || (v == bv && ii < bix)){ bv = v; bix = ii; }
    }
    nll = __logf(gs) + gm - tgtl[(size_t)s * cB + b];
    int tgt = (s < cL) ? ys[b * cL + s] : EOS;
    cor = (bix == tgt) ? 1.f : 0.f;
  }
  #pragma unroll
  for (int m = 1; m < 64; m <<= 1){
    nll += __shfl_xor(nll, m, 64); cor += __shfl_xor(cor, m, 64);
  }
  if (tid == 0){ cestep[s * 2] = nll; cestep[s * 2 + 1] = cor; }
}

__global__ __launch_bounds__(256) void k_ce3(const float* __restrict__ cestep,
                                             float* __restrict__ out){
  int tid = threadIdx.x;
  float nll = 0.f, cor = 0.f;
  for (int s = tid; s < cNS; s += 256){ nll += cestep[s * 2]; cor += cestep[s * 2 + 1]; }
  __shared__ float sn[4], sc_[4];
  int w = tid >> 6, l = tid & 63;
  #pragma unroll
  for (int m = 1; m < 64; m <<= 1){
    nll += __shfl_xor(nll, m, 64); cor += __shfl_xor(cor, m, 64);
  }
  if (l == 0){ sn[w] = nll; sc_[w] = cor; }
  __syncthreads();
  if (tid == 0){
    float a = sn[0] + sn[1] + sn[2] + sn[3];
    float b = sc_[0] + sc_[1] + sc_[2] + sc_[3];
    out[0] = a / (float)(cB * cNS) * (float)cL;
    out[1] = b / (float)(cB * cNS);
  }
}

// ------------------------------- host --------------------------------------
extern "C" void kernel_launch(void* const* d_in, const int* in_sizes, int n_in,
                              void* d_out, int out_size, void* d_ws, size_t ws_size,
                              hipStream_t stream){
  const float* hpad = (const float*)d_in[0];
  const int*   hlen = (const int*)d_in[1];
  const int*   ys   = (const int*)d_in[2];
  const float* embed= (const float*)d_in[3];
  const float* Wout = (const float*)d_in[4];
  const float* bout = (const float*)d_in[5];
  const float* Wenc = (const float*)d_in[6];
  const float* Wdec = (const float*)d_in[7];
  const float* vatt = (const float*)d_in[8];
  const float* Wih0 = (const float*)d_in[9];
  const float* bih0 = (const float*)d_in[10];
  const float* Whh0 = (const float*)d_in[11];
  const float* bhh0 = (const float*)d_in[12];
  const float* Wih1 = (const float*)d_in[13];
  const float* bih1 = (const float*)d_in[14];
  const float* Whh1 = (const float*)d_in[15];
  const float* bhh1 = (const float*)d_in[16];
  (void)in_sizes; (void)n_in; (void)out_size; (void)ws_size;

  char* base = (char*)d_ws;
  size_t off = 0;
  auto alloc = [&](size_t bytes) -> void* {
    void* r = base + off; off += (bytes + 255) & ~(size_t)255; return r;
  };
  u32*   ctl     = (u32*)  alloc(1024);
  u16*   hpadM   = (u16*)  alloc((size_t)cB * cT * cE * 2);
  u8*    ph8     = (u8*)   alloc((size_t)cB * cT * 1024);
  u16*   embb    = (u16*)  alloc((size_t)cV * cD * 2);
  u16*   ey      = (u16*)  alloc((size_t)cNS * cB * cD * 2);
  u16*   eyproj  = (u16*)  alloc((size_t)cNS * cB * 4096 * 2);
  u16*   z1all   = (u16*)  alloc((size_t)(cNS + 1) * cB * cD * 2);
  u16*   WencT   = (u16*)  alloc((size_t)cA * cE * 2);
  u16*   Wih0m   = (u16*)  alloc((size_t)4096 * cD * 2);
  u16*   Woutb   = (u16*)  alloc((size_t)cV * cD * 2);
  u8*    Wapf8   = (u8*)   alloc((size_t)4096 * 512);
  u8*    Wih1f8  = (u8*)   alloc((size_t)4096 * 1024);
  u8*    Whh1f8  = (u8*)   alloc((size_t)4096 * 1024);
  u8*    Whh0f8  = (u8*)   alloc((size_t)4096 * 1024);
  u8*    WdecTf8 = (u8*)   alloc((size_t)512 * 1024);
  float* bias01  = (float*)alloc(4096 * 4);
  u32*   qt      = (u32*)  alloc((size_t)cB * cA * 4);
  float* att_acc = (float*)alloc((size_t)2 * cB * cE * 4);
  float* att_l   = (float*)alloc((size_t)2 * cB * 4);
  u32*   g0t     = (u32*)  alloc((size_t)cB * 4096 * 4);
  u32*   hh1t    = (u32*)  alloc((size_t)cB * 4096 * 4);
  u16*   z0t     = (u16*)  alloc((size_t)cB * cD * 2);
  u16*   z1t     = (u16*)  alloc((size_t)cB * cD * 2);
  float* c0      = (float*)alloc((size_t)2 * cB * cD * 4);
  float* c1      = (float*)alloc((size_t)2 * cB * cD * 4);
  float* pmax    = (float*)alloc((size_t)cNS * cB * 40 * 4);
  float* psum    = (float*)alloc((size_t)cNS * cB * 40 * 4);
  int*   pai     = (int*)  alloc((size_t)cNS * cB * 40 * 4);
  float* tgtl    = (float*)alloc((size_t)cNS * cB * 4);
  float* cestep  = (float*)alloc((size_t)cNS * 2 * 4);

  k_init<<<64, 256, 0, stream>>>(ctl, qt, c0, c1, z1t, att_acc, att_l);
  k_cvt<<<2048, 256, 0, stream>>>(hpad, hpadM, cB * cT * cE / 4);
  k_cvt8I<<<1024, 256, 0, stream>>>(hpad, ph8, cB * cT * 64);
  k_cvt<<<2048, 256, 0, stream>>>(embed, embb, cV * cD / 4);
  k_cvt<<<2048, 256, 0, stream>>>(Wout, Woutb, cV * cD / 4);
  k_slice<<<1024, 256, 0, stream>>>(Wih0, Wih0m, 4096 * cD, 10, 1536, 0);
  k_transp<<<256, 256, 0, stream>>>(Wenc, WencT, cA * cE, 9, cA);
  k_bias<<<16, 256, 0, stream>>>(bih1, bhh1, bias01, 4096);
  k_wf8perm<<<512, 256, 0, stream>>>(Wih0, Wapf8, 4096 * 512 / 4, 9, 1536, 1024);
  k_wf8perm<<<1024, 256, 0, stream>>>(Wih1, Wih1f8, 4096 * 1024 / 4, 10, 1024, 0);
  k_wf8<<<1024, 256, 0, stream>>>(Whh1, Whh1f8, 4096 * 1024 / 4);
  k_wf8<<<1024, 256, 0, stream>>>(Whh0, Whh0f8, 4096 * 1024 / 4);
  k_wf8t<<<128, 256, 0, stream>>>(Wdec, WdecTf8, 512 * 1024 / 4);
  k_gather<<<1200, 256, 0, stream>>>(embb, ys, ey, cNS * cB * 128);
  k_pe2<<<200, 512, 0, stream>>>(hpadM, WencT, ph8);
  k_ey2<<<dim3(38, 8), 512, 0, stream>>>(ey, Wih0m, bih0, bhh0, eyproj, g0t);

  LoopArgs la;
  la.hlen = hlen; la.ph8 = ph8; la.eyproj = eyproj;
  la.Wapf8 = Wapf8; la.Whh1f8 = Whh1f8; la.Wih1f8 = Wih1f8;
  la.Whh0f8 = Whh0f8; la.WdecTf8 = WdecTf8;
  la.vatt = vatt; la.bias01 = bias01;
  la.qt = qt; la.att_acc = att_acc; la.att_l = att_l;
  la.g0t = g0t; la.hh1t = hh1t; la.z0t = z0t; la.z1t = z1t;
  la.c0 = c0; la.c1 = c1; la.z1all = z1all; la.ctl = ctl;
  k_loop<<<NBLK, 512, 0, stream>>>(la);

  k_ce1<<<1200, 256, 0, stream>>>(z1all, Woutb, bout, ys, pmax, psum, pai, tgtl);
  k_ce2<<<cNS, 64, 0, stream>>>(pmax, psum, pai, tgtl, ys, cestep);
  k_ce3<<<1, 256, 0, stream>>>(cestep, (float*)d_out);
}

// Round 7
// 5721.727 us; speedup vs baseline: 1.4089x; 1.4089x over previous
//
#include <hip/hip_runtime.h>

// ---------------------------------------------------------------------------
// Decoder_60868276519063: attention-LSTM decoder forward (loss, acc)
// B=32 T=800 E=512 D=1024 V=5000 L=149 (150 steps) A=512
// Round 7: barrier-free counter-gated dataflow (tiny 32B polls, 8-way spread
// counters), direct-from-L3 MFMA operands (no LDS x staging), LDS-resident
// attention, fp8 MFMA GEMVs with register-resident weights.
// ---------------------------------------------------------------------------

typedef unsigned short u16;
typedef unsigned char u8;
typedef unsigned int u32;
typedef long long i64;
typedef unsigned long long u64;
typedef float f32x4 __attribute__((ext_vector_type(4)));
typedef float f32x2 __attribute__((ext_vector_type(2)));
typedef short s16x8 __attribute__((ext_vector_type(8)));

constexpr int cB = 32, cT = 800, cE = 512, cD = 1024, cV = 5000, cL = 149,
              cNS = 150, cA = 512;
constexpr int SOS = 1, EOS = 2;
constexpr int NBLK = 256;
constexpr float DS = 1.0f / 128.0f;   // fp8 descale: W x16, x x8

// ctl word indices (u32 units, counters spread over 8 lines of 64B)
constexpr int ACNT = 0, Z0CNT = 128, HH1CNT = 256, Z1CNT = 384, G0CNT = 512,
              QCNT = 640, SCNT = 768 /* +p*128 */, ZDONE = 1024 /* +p*16 */;

__device__ __forceinline__ float bf2f(u16 x){
  union { u32 u; float f; } v; v.u = ((u32)x) << 16; return v.f;
}
__device__ __forceinline__ u16 f2bf(float f){
  union { float f; u32 u; } v; v.f = f;
  u32 r = v.u + 0x7FFFu + ((v.u >> 16) & 1u);
  return (u16)(r >> 16);
}
__device__ __forceinline__ float frcp(float x){ return __builtin_amdgcn_rcpf(x); }
__device__ __forceinline__ float fsigm(float x){ return frcp(1.f + __expf(-x)); }
__device__ __forceinline__ float ftanh(float x){
  float u = __expf(2.f * x);
  return 1.f - 2.f * frcp(u + 1.f);
}
__device__ __forceinline__ f32x4 MFMA(s16x8 a, s16x8 b, f32x4 c){
  return __builtin_amdgcn_mfma_f32_16x16x32_bf16(a, b, c, 0, 0, 0);
}
__device__ __forceinline__ f32x4 MFMA8(i64 a, i64 b, f32x4 c){
  return __builtin_amdgcn_mfma_f32_16x16x32_fp8_fp8(a, b, c, 0, 0, 0);
}
__device__ __forceinline__ s16x8 LD8(const u16* p){ return *(const s16x8*)p; }
__device__ __forceinline__ u8 f2fp8(float x){
  return (u8)(__builtin_amdgcn_cvt_pk_fp8_f32(x, x, 0, false) & 0xFF);
}
__device__ __forceinline__ u32 pk4(float a, float b, float c, float d){
  u32 w = (u32)__builtin_amdgcn_cvt_pk_fp8_f32(a, b, 0, false);
  w = (u32)__builtin_amdgcn_cvt_pk_fp8_f32(c, d, (int)w, true);
  return w;
}
__device__ __forceinline__ void unpack8(u32 lo, u32 hi, float* o){
  f32x2 a = __builtin_amdgcn_cvt_pk_f32_fp8((int)lo, false);
  f32x2 b = __builtin_amdgcn_cvt_pk_f32_fp8((int)lo, true);
  f32x2 c = __builtin_amdgcn_cvt_pk_f32_fp8((int)hi, false);
  f32x2 d = __builtin_amdgcn_cvt_pk_f32_fp8((int)hi, true);
  o[0]=a[0]; o[1]=a[1]; o[2]=b[0]; o[3]=b[1];
  o[4]=c[0]; o[5]=c[1]; o[6]=d[0]; o[7]=d[1];
}

// ---- agent-scope (sc1) relaxed accessors (coherent at L3, no fences) ------
__device__ __forceinline__ float ld_sc(const float* p){
  return __hip_atomic_load(p, __ATOMIC_RELAXED, __HIP_MEMORY_SCOPE_AGENT);
}
__device__ __forceinline__ void st_sc(float* p, float v){
  __hip_atomic_store(p, v, __ATOMIC_RELAXED, __HIP_MEMORY_SCOPE_AGENT);
}
__device__ __forceinline__ u64 ld_sc8(const void* p){
  return __hip_atomic_load((const u64*)p, __ATOMIC_RELAXED, __HIP_MEMORY_SCOPE_AGENT);
}
__device__ __forceinline__ u32 ld_su(const u32* p){
  return __hip_atomic_load(p, __ATOMIC_RELAXED, __HIP_MEMORY_SCOPE_AGENT);
}
__device__ __forceinline__ void st_su(u32* p, u32 v){
  __hip_atomic_store(p, v, __ATOMIC_RELAXED, __HIP_MEMORY_SCOPE_AGENT);
}
__device__ __forceinline__ void st_scb(u8* p, u8 v){
  __hip_atomic_store(p, v, __ATOMIC_RELAXED, __HIP_MEMORY_SCOPE_AGENT);
}

// gate: poll sum of 8 spread words >= target (one lane; 32B per retry)
__device__ __forceinline__ void gate8(const u32* c, u32 target){
  for(;;){
    u32 s = 0;
    #pragma unroll
    for (int i = 0; i < 8; ++i) s += ld_su(c + i * 16);
    if (s >= target) break;
    __builtin_amdgcn_s_sleep(1);
  }
}
__device__ __forceinline__ void inc8(u32* c, int blk){
  asm volatile("s_waitcnt vmcnt(0)" ::: "memory");
  __hip_atomic_fetch_add(c + (blk & 7) * 16, 1u, __ATOMIC_RELAXED,
                         __HIP_MEMORY_SCOPE_AGENT);
}

// ------------------------------- prologue ----------------------------------
__global__ void k_init(u32* ctl, float* q, float* c0, float* c1, u8* z1f8,
                       float* att_acc, float* att_l){
  int i = blockIdx.x * blockDim.x + threadIdx.x, n = gridDim.x * blockDim.x;
  for (int k = i; k < 1152; k += n) ctl[k] = 0;
  for (int k = i; k < cB * cA; k += n) q[k] = 0.f;
  for (int k = i; k < 2 * cB * cD; k += n){ c0[k] = 0.f; c1[k] = 0.f; }
  for (int k = i; k < cB * cD / 4; k += n) ((u32*)z1f8)[k] = 0;
  for (int k = i; k < 2 * cB * cE; k += n) att_acc[k] = 0.f;
  for (int k = i; k < 2 * cB; k += n) att_l[k] = 0.f;
}

__global__ void k_cvt(const float* __restrict__ s, u16* __restrict__ d, int n4){
  int i = blockIdx.x * blockDim.x + threadIdx.x, st = gridDim.x * blockDim.x;
  for (int k = i; k < n4; k += st){
    float4 v = ((const float4*)s)[k];
    ushort4 o; o.x = f2bf(v.x); o.y = f2bf(v.y); o.z = f2bf(v.z); o.w = f2bf(v.w);
    ((ushort4*)d)[k] = o;
  }
}

// hpad -> fp8 h-half of interleaved ph8 rows: [grp*16+8 .. +15]
__global__ void k_cvt8I(const float* __restrict__ s, u8* __restrict__ d, int n){
  int i = blockIdx.x * blockDim.x + threadIdx.x, st = gridDim.x * blockDim.x;
  for (int k = i; k < n; k += st){
    int row = k >> 6, grp = k & 63;
    const float4* p = (const float4*)(s + (size_t)row * 512 + grp * 8);
    float4 v0 = p[0], v1 = p[1];
    u32 lo = pk4(v0.x, v0.y, v0.z, v0.w);
    u32 hi = pk4(v1.x, v1.y, v1.z, v1.w);
    *(uint2*)(d + (size_t)row * 1024 + grp * 16 + 8) = make_uint2(lo, hi);
  }
}

__global__ void k_slice(const float* __restrict__ s, u16* __restrict__ d, int n,
                        int cshift, int srcld, int coff){
  int i = blockIdx.x * blockDim.x + threadIdx.x, st = gridDim.x * blockDim.x;
  int cmask = (1 << cshift) - 1;
  for (int k = i; k < n; k += st){
    int r = k >> cshift, c = k & cmask;
    d[k] = f2bf(s[(size_t)r * srcld + coff + c]);
  }
}

__global__ void k_transp(const float* __restrict__ s, u16* __restrict__ d, int n,
                         int rshift, int csrc){
  int i = blockIdx.x * blockDim.x + threadIdx.x, st = gridDim.x * blockDim.x;
  int mask = (1 << rshift) - 1;
  for (int k = i; k < n; k += st){
    int dd = k & mask, a = k >> rshift;
    d[k] = f2bf(s[(size_t)dd * csrc + a]);
  }
}

__global__ void k_bias(const float* a, const float* b, float* o, int n){
  int i = blockIdx.x * blockDim.x + threadIdx.x, st = gridDim.x * blockDim.x;
  for (int k = i; k < n; k += st) o[k] = a[k] + b[k];
}

// fp8 weight convert, x16 scale, row-permuted: dst row R=j*32+jj, jj=g*8+c
__global__ void k_wf8perm(const float* __restrict__ s, u8* __restrict__ d,
                          int n4, int kshift, int srcld, int coff){
  int i = blockIdx.x * blockDim.x + threadIdx.x, st = gridDim.x * blockDim.x;
  int kmask = (1 << kshift) - 1;
  for (int k = i; k < n4; k += st){
    int flat = k * 4;
    int R = flat >> kshift, kk = flat & kmask;
    int j = R >> 5, jj = R & 31, g = jj >> 3, c = jj & 7;
    const float* p = s + (size_t)(g * 1024 + j * 8 + c) * srcld + coff + kk;
    ((u32*)d)[k] = pk4(p[0]*16.f, p[1]*16.f, p[2]*16.f, p[3]*16.f);
  }
}

__global__ void k_wf8(const float* __restrict__ s, u8* __restrict__ d, int n4){
  int i = blockIdx.x * blockDim.x + threadIdx.x, st = gridDim.x * blockDim.x;
  for (int k = i; k < n4; k += st){
    float4 v = ((const float4*)s)[k];
    ((u32*)d)[k] = pk4(v.x*16.f, v.y*16.f, v.z*16.f, v.w*16.f);
  }
}

// WdecT fp8: dst[a][dd] = Wdec[dd][a] * 16, dst [512][1024]
__global__ void k_wf8t(const float* __restrict__ s, u8* __restrict__ d, int n4){
  int i = blockIdx.x * blockDim.x + threadIdx.x, st = gridDim.x * blockDim.x;
  for (int k = i; k < n4; k += st){
    int flat = k * 4;
    int a = flat >> 10, dd = flat & 1023;
    ((u32*)d)[k] = pk4(s[(size_t)(dd+0)*512 + a]*16.f,
                       s[(size_t)(dd+1)*512 + a]*16.f,
                       s[(size_t)(dd+2)*512 + a]*16.f,
                       s[(size_t)(dd+3)*512 + a]*16.f);
  }
}

// ey[r][:] = embb[tok(r)][:]  (bf16 gather), r = s*32+b
__global__ void k_gather(const u16* __restrict__ embb, const int* __restrict__ ys,
                         u16* __restrict__ ey, int n16){
  int i = blockIdx.x * blockDim.x + threadIdx.x, st = gridDim.x * blockDim.x;
  for (int k = i; k < n16; k += st){
    int r = k >> 7, seg = k & 127;
    int s = r >> 5, b = r & 31;
    int tok = (s == 0) ? SOS : ys[b * cL + (s - 1)];
    ((uint4*)ey)[(size_t)r * 128 + seg] =
        ((const uint4*)embb)[(size_t)tok * 128 + seg];
  }
}

// pe GEMM: [25600x512] @ WencT[512 a][512 e]^T -> fp8 into ph8 pe-half
__global__ __launch_bounds__(512, 1) void k_pe2(const u16* __restrict__ A,
    const u16* __restrict__ Bw, u8* __restrict__ ph8){
  int tid = threadIdx.x, w = tid >> 6, l = tid & 63;
  int col = l & 15, kin = 8 * (l >> 4);
  int mw = w >> 2, nw = w & 3;
  int m0 = blockIdx.x * 128 + mw * 64;
  int n0 = nw * 128;
  f32x4 acc[4][8] = {};
  for (int kc = 0; kc < 16; ++kc){
    int k = kc * 32 + kin;
    s16x8 af[4], bf[8];
    #pragma unroll
    for (int i = 0; i < 4; ++i) af[i] = LD8(A + (size_t)(m0 + i*16 + col)*512 + k);
    #pragma unroll
    for (int j = 0; j < 8; ++j) bf[j] = LD8(Bw + (size_t)(n0 + j*16 + col)*512 + k);
    #pragma unroll
    for (int i = 0; i < 4; ++i)
      #pragma unroll
      for (int j = 0; j < 8; ++j) acc[i][j] = MFMA(af[i], bf[j], acc[i][j]);
  }
  int hi4 = (l >> 4) * 4;
  #pragma unroll
  for (int i = 0; i < 4; ++i)
    #pragma unroll
    for (int j = 0; j < 8; ++j){
      int a0 = n0 + j * 16 + col;
      size_t boff = ((size_t)(a0 >> 3) << 4) + (a0 & 7);
      #pragma unroll
      for (int r = 0; r < 4; ++r){
        int row = m0 + i * 16 + hi4 + r;
        ph8[(size_t)row * 1024 + boff] = f2fp8(acc[i][j][r]);
      }
    }
}

// eyproj GEMM: ey[4800x1024] @ Wih0m[4096x1024]^T + biases -> bf16 (+g0 f32)
__global__ __launch_bounds__(512, 1) void k_ey2(const u16* __restrict__ ey,
    const u16* __restrict__ Wm, const float* __restrict__ bih0,
    const float* __restrict__ bhh0, u16* __restrict__ eyproj,
    float* __restrict__ g0buf){
  int tid = threadIdx.x, w = tid >> 6, l = tid & 63;
  int col = l & 15, kin = 8 * (l >> 4);
  int mw = w >> 2, nw = w & 3;
  int m0 = blockIdx.x * 128 + mw * 64;
  int n0 = blockIdx.y * 512 + nw * 128;
  f32x4 acc[4][8] = {};
  for (int kc = 0; kc < 32; ++kc){
    int k = kc * 32 + kin;
    s16x8 af[4], bf[8];
    #pragma unroll
    for (int i = 0; i < 4; ++i){
      int ar = m0 + i * 16 + col; ar = (ar < 4800) ? ar : 0;
      af[i] = LD8(ey + (size_t)ar * 1024 + k);
    }
    #pragma unroll
    for (int j = 0; j < 8; ++j) bf[j] = LD8(Wm + (size_t)(n0 + j*16 + col)*1024 + k);
    #pragma unroll
    for (int i = 0; i < 4; ++i)
      #pragma unroll
      for (int j = 0; j < 8; ++j) acc[i][j] = MFMA(af[i], bf[j], acc[i][j]);
  }
  int hi4 = (l >> 4) * 4;
  #pragma unroll
  for (int i = 0; i < 4; ++i)
    #pragma unroll
    for (int j = 0; j < 8; ++j){
      int jc = n0 + j * 16 + col;
      float bj = bih0[jc] + bhh0[jc];
      #pragma unroll
      for (int r = 0; r < 4; ++r){
        int row = m0 + i * 16 + hi4 + r;
        if (row < 4800){
          float val = acc[i][j][r] + bj;
          eyproj[(size_t)row * 4096 + jc] = f2bf(val);
          if (row < 32) g0buf[(size_t)row * 4096 + jc] = val;
        }
      }
    }
}

// ------------------------------ main loop ----------------------------------
struct LoopArgs {
  const int* hlen;
  const u8* ph8;
  const u16* eyproj;
  const u8* Wapf8; const u8* Whh1f8; const u8* Wih1f8; const u8* Whh0f8;
  const u8* WdecTf8;
  const float* vatt; const float* bias01;
  float* q; float* att_acc; float* att_l;
  float* g0buf; float* hh1buf; u8* z0f8; u8* z1f8;
  float* c0; float* c1; u16* z1all;
  u32* ctl;
};

struct P1Lds { float red[8][512]; float ls[8]; };
struct GvLds { float acc[8][2][16][17]; };
union LoopLds { P1Lds p1; GvLds gv; };

// GEMV with direct-from-global fp8 x operand (z buffers, 32 rows x 1024)
template<int KH, int ITERS>
__device__ __forceinline__ void gemv_dirz(const i64* wreg, const u8* zg,
                                          LoopLds& L, int tid){
  const int w = tid >> 6, l = tid & 63;
  const int col = l & 15, kin = 8 * (l >> 4);
  const int kh = (KH == 4) ? (w & 3) : (w & 1);
  constexpr int KB = ITERS * 32;
  const u8* xr = zg + (size_t)col * 1024 + kh * KB + kin;
  i64 x0[ITERS], x1[ITERS];
  #pragma unroll
  for (int kc = 0; kc < ITERS; ++kc){
    x0[kc] = (i64)ld_sc8(xr + kc * 32);
    x1[kc] = (i64)ld_sc8(xr + 16 * 1024 + kc * 32);
  }
  f32x4 a0 = {0.f,0.f,0.f,0.f}, a1 = {0.f,0.f,0.f,0.f};
  #pragma unroll
  for (int kc = 0; kc < ITERS; ++kc){
    a0 = MFMA8(x0[kc], wreg[kc], a0);
    a1 = MFMA8(x1[kc], wreg[kc], a1);
  }
  const int hi4 = (l >> 4) * 4;
  #pragma unroll
  for (int r = 0; r < 4; ++r){
    L.gv.acc[w][0][hi4 + r][col] = a0[r];
    L.gv.acc[w][1][hi4 + r][col] = a1[r];
  }
}

// Wa GEMV: x = normalize(att_acc)*8 packed to fp8 in-register (K=512, KH=4)
__device__ __forceinline__ void gemv_att(const i64* wreg, const float* aacc,
                                         const float* al, LoopLds& L, int tid){
  const int w = tid >> 6, l = tid & 63;
  const int col = l & 15, kin = 8 * (l >> 4);
  const int kh = w & 3;
  const float* ar0 = aacc + (size_t)col * 512 + kh * 128 + kin;
  const float* ar1 = aacc + (size_t)(col + 16) * 512 + kh * 128 + kin;
  float s0 = 8.f * frcp(ld_sc(al + col));
  float s1 = 8.f * frcp(ld_sc(al + col + 16));
  u64 v0[16], v1[16];
  #pragma unroll
  for (int kc = 0; kc < 4; ++kc){
    #pragma unroll
    for (int j = 0; j < 4; ++j){
      v0[kc*4+j] = ld_sc8(ar0 + kc * 32 + j * 2);
      v1[kc*4+j] = ld_sc8(ar1 + kc * 32 + j * 2);
    }
  }
  f32x4 a0 = {0.f,0.f,0.f,0.f}, a1 = {0.f,0.f,0.f,0.f};
  #pragma unroll
  for (int kc = 0; kc < 4; ++kc){
    union { u64 q; u32 d[2]; } t0, t1;
    #pragma unroll
    for (int h = 0; h < 2; ++h){
      union { u64 q; float f[2]; } aa, bb;
      aa.q = v0[kc*4 + h*2]; bb.q = v0[kc*4 + h*2 + 1];
      t0.d[h] = pk4(aa.f[0]*s0, aa.f[1]*s0, bb.f[0]*s0, bb.f[1]*s0);
      aa.q = v1[kc*4 + h*2]; bb.q = v1[kc*4 + h*2 + 1];
      t1.d[h] = pk4(aa.f[0]*s1, aa.f[1]*s1, bb.f[0]*s1, bb.f[1]*s1);
    }
    a0 = MFMA8((i64)t0.q, wreg[kc], a0);
    a1 = MFMA8((i64)t1.q, wreg[kc], a1);
  }
  const int hi4 = (l >> 4) * 4;
  #pragma unroll
  for (int r = 0; r < 4; ++r){
    L.gv.acc[w][0][hi4 + r][col] = a0[r];
    L.gv.acc[w][1][hi4 + r][col] = a1[r];
  }
}

__global__ __launch_bounds__(512, 1) void k_loop(LoopArgs g_){
  __shared__ __align__(16) LoopLds L;
  __shared__ __align__(16) u8 ph8_lds[100 * 1024];
  const int blk = blockIdx.x, tid = threadIdx.x;
  const int w = tid >> 6, l = tid & 63;
  const int col = l & 15, kin = 8 * (l >> 4);
  const int b_att = blk >> 3, oct = blk & 7;
  const int hl = g_.hlen[b_att];
  const int t0 = oct * 100;
  const int t1 = (t0 + 100 < hl) ? t0 + 100 : hl;
  const int nrow = t1 - t0;
  u32* ctl = g_.ctl;
  float vv[8];
  #pragma unroll
  for (int i = 0; i < 8; ++i) vv[i] = g_.vatt[l * 8 + i];
  for (int idx = tid; idx < nrow * 64; idx += 512){
    int rr = idx >> 6, gg = idx & 63;
    *(uint4*)&ph8_lds[rr * 1024 + gg * 16] =
        *(const uint4*)(g_.ph8 + ((size_t)b_att * cT + t0 + rr) * 1024 + gg * 16);
  }
  // ---- preload step-invariant weight fragments into registers ----
  i64 wB[8], wC[16];
  {
    const int nt4 = w >> 2, kh4 = w & 3;
    const int nt2 = w >> 1, kh2 = w & 1;
    if (blk < 128){
      const u8* wr = g_.Wapf8 + (size_t)blk * 32 * 512 +
                     (size_t)(nt4 * 16 + col) * 512 + kh4 * 128 + kin;
      #pragma unroll
      for (int kc = 0; kc < 4; ++kc) wB[kc] = *(const i64*)(wr + kc * 32);
      const u8* wr2 = g_.Wih1f8 + (size_t)blk * 32 * 1024 +
                      (size_t)(nt4 * 16 + col) * 1024 + kh4 * 256 + kin;
      #pragma unroll
      for (int kc = 0; kc < 8; ++kc) wC[kc] = *(const i64*)(wr2 + kc * 32);
    } else {
      const u8* wr = g_.Whh1f8 + (size_t)(blk - 128) * 32 * 1024 +
                     (size_t)(nt4 * 16 + col) * 1024 + kh4 * 256 + kin;
      #pragma unroll
      for (int kc = 0; kc < 8; ++kc) wB[kc] = *(const i64*)(wr + kc * 32);
      if (blk < 192){
        const u8* wr2 = g_.Whh0f8 + (size_t)(blk - 128) * 64 * 1024 +
                        (size_t)(nt2 * 16 + col) * 1024 + kh2 * 512 + kin;
        #pragma unroll
        for (int kc = 0; kc < 16; ++kc) wC[kc] = *(const i64*)(wr2 + kc * 32);
      } else if (blk < 208){
        const u8* wr2 = g_.WdecTf8 + (size_t)(blk - 192) * 32 * 1024 +
                        (size_t)(nt4 * 16 + col) * 1024 + kh4 * 256 + kin;
        #pragma unroll
        for (int kc = 0; kc < 8; ++kc) wC[kc] = *(const i64*)(wr2 + kc * 32);
      }
    }
  }
  __syncthreads();

  for (int s = 0; s < cNS; ++s){
    const int p = s & 1;
    // ================= A: attention ======================================
    if (tid == 0){
      gate8(ctl + QCNT, 16u * (u32)s);               // q(s) ready
      if (nrow > 0){
        u32 need = (u32)(s >> 1);                    // att_acc[p] re-zeroed
        while (ld_su(&ctl[ZDONE + p * 16]) < need) __builtin_amdgcn_s_sleep(2);
      }
    }
    __syncthreads();
    if (nrow > 0){
      float qv[8];
      const float* qb = g_.q + b_att * cA + l * 8;
      #pragma unroll
      for (int i = 0; i < 8; ++i) qv[i] = ld_sc(qb + i);
      float acc8[8] = {0.f,0.f,0.f,0.f,0.f,0.f,0.f,0.f};
      float lsum = 0.f;
      for (int t = t0 + w; t < t1; t += 8){
        uint4 v = *(const uint4*)&ph8_lds[(t - t0) * 1024 + l * 16];
        float x[8]; unpack8(v.x, v.y, x);
        float e_ = 0.f;
        #pragma unroll
        for (int i = 0; i < 8; ++i) e_ += vv[i] * ftanh(x[i] + qv[i]);
        #pragma unroll
        for (int m = 1; m < 64; m <<= 1) e_ += __shfl_xor(e_, m, 64);
        float wt = __expf(e_);          // |e| <= sum|v_att| ~ 8.2
        lsum += wt;
        float h[8]; unpack8(v.z, v.w, h);
        #pragma unroll
        for (int i = 0; i < 8; ++i) acc8[i] = fmaf(wt, h[i], acc8[i]);
      }
      *(f32x4*)&L.p1.red[w][l * 8]     = *(f32x4*)&acc8[0];
      *(f32x4*)&L.p1.red[w][l * 8 + 4] = *(f32x4*)&acc8[4];
      if (l == 0) L.p1.ls[w] = lsum;
      __syncthreads();
      float vsum = 0.f;
      #pragma unroll
      for (int ww = 0; ww < 8; ++ww) vsum += L.p1.red[ww][tid];
      atomicAdd(&g_.att_acc[((size_t)p * cB + b_att) * cE + tid], vsum);
      if (tid == 0){
        float ls = 0.f;
        #pragma unroll
        for (int i = 0; i < 8; ++i) ls += L.p1.ls[i];
        atomicAdd(&g_.att_l[p * cB + b_att], ls);
      }
    }
    __syncthreads();
    if (tid == 0) inc8(ctl + ACNT, blk);
    // ================= B =================================================
    if (blk < 128){
      if (tid == 0){
        gate8(ctl + ACNT, 256u * (u32)(s + 1));      // att adds complete
        gate8(ctl + G0CNT, 64u * (u32)s);            // g0(s) ready
      }
      __syncthreads();
      gemv_att(wB, g_.att_acc + (size_t)p * cB * cE, g_.att_l + p * cB, L, tid);
      __syncthreads();
      if (tid == 0) inc8(ctl + SCNT + p * 128, blk); // att buffer consumed
      if (tid < 256){
        int bb = tid >> 3, dc = tid & 7, d = blk * 8 + dc;
        int mt = bb >> 4, rr = bb & 15;
        float gate[4];
        #pragma unroll
        for (int g = 0; g < 4; ++g){
          int jj = g * 8 + dc;
          float v = 0.f;
          #pragma unroll
          for (int kh = 0; kh < 4; ++kh)
            v += L.gv.acc[(jj >> 4) * 4 + kh][mt][rr][jj & 15];
          gate[g] = v * DS +
                    ld_sc(&g_.g0buf[(size_t)p * cB * 4096 + bb * 4096 + g * 1024 + d]);
        }
        float c = fsigm(gate[1]) * g_.c0[(size_t)p * cB * cD + bb * cD + d] +
                  fsigm(gate[0]) * ftanh(gate[2]);
        float z = fsigm(gate[3]) * ftanh(c);
        g_.c0[(size_t)(p ^ 1) * cB * cD + bb * cD + d] = c;
        st_scb(&g_.z0f8[bb * cD + d], f2fp8(z * 8.f));
      }
      __syncthreads();
      if (tid == 0) inc8(ctl + Z0CNT, blk);
    } else {
      if (tid == 0) gate8(ctl + Z1CNT, 128u * (u32)s);   // z1(s) ready
      __syncthreads();
      gemv_dirz<4, 8>(wB, g_.z1f8, L, tid);
      __syncthreads();
      {
        const int jb = (blk - 128) * 32;
        int bb = tid >> 4, j2 = (tid & 15) * 2;
        int mt = bb >> 4, rr = bb & 15;
        #pragma unroll
        for (int k = 0; k < 2; ++k){
          int jj = j2 + k;
          float v = 0.f;
          #pragma unroll
          for (int kh = 0; kh < 4; ++kh)
            v += L.gv.acc[(jj >> 4) * 4 + kh][mt][rr][jj & 15];
          st_sc(&g_.hh1buf[bb * 4096 + jb + jj], v * DS + g_.bias01[jb + jj]);
        }
      }
      __syncthreads();
      if (tid == 0) inc8(ctl + HH1CNT, blk);
    }
    // ================= C =================================================
    if (blk < 128){
      if (tid == 0){
        gate8(ctl + Z0CNT, 128u * (u32)(s + 1));
        gate8(ctl + HH1CNT, 128u * (u32)(s + 1));
      }
      __syncthreads();
      gemv_dirz<4, 8>(wC, g_.z0f8, L, tid);
      __syncthreads();
      if (tid < 256){
        int bb = tid >> 3, dc = tid & 7, d = blk * 8 + dc;
        int mt = bb >> 4, rr = bb & 15;
        float gate[4];
        #pragma unroll
        for (int g = 0; g < 4; ++g){
          int jj = g * 8 + dc;
          float v = 0.f;
          #pragma unroll
          for (int kh = 0; kh < 4; ++kh)
            v += L.gv.acc[(jj >> 4) * 4 + kh][mt][rr][jj & 15];
          gate[g] = v * DS + ld_sc(&g_.hh1buf[bb * 4096 + g * 1024 + d]);
        }
        float c = fsigm(gate[1]) * g_.c1[(size_t)p * cB * cD + bb * cD + d] +
                  fsigm(gate[0]) * ftanh(gate[2]);
        float z = fsigm(gate[3]) * ftanh(c);
        g_.c1[(size_t)(p ^ 1) * cB * cD + bb * cD + d] = c;
        g_.z1all[((size_t)s + 1) * cB * cD + bb * cD + d] = f2bf(z);
        st_scb(&g_.z1f8[bb * cD + d], f2fp8(z * 8.f));
      }
      __syncthreads();
      if (tid == 0) inc8(ctl + Z1CNT, blk);
    } else if (blk < 192){
      if (tid == 0) gate8(ctl + Z0CNT, 128u * (u32)(s + 1));
      __syncthreads();
      gemv_dirz<2, 16>(wC, g_.z0f8, L, tid);
      __syncthreads();
      if (s < cNS - 1){
        const int jb = (blk - 128) * 64;
        int bb = tid >> 4, j4 = (tid & 15) * 4;
        int mt = bb >> 4, rr = bb & 15;
        const u16* eyr = g_.eyproj + (((size_t)(s + 1) * cB + bb) * 4096) + jb + j4;
        #pragma unroll
        for (int k = 0; k < 4; ++k){
          int jj = j4 + k;
          float v = 0.f;
          #pragma unroll
          for (int kh = 0; kh < 2; ++kh)
            v += L.gv.acc[(jj >> 4) * 2 + kh][mt][rr][jj & 15];
          st_sc(&g_.g0buf[(size_t)(p ^ 1) * cB * 4096 + bb * 4096 + jb + jj],
                v * DS + bf2f(eyr[k]));
        }
      }
      __syncthreads();
      if (tid == 0) inc8(ctl + G0CNT, blk);
    } else if (blk < 208){
      if (tid == 0) gate8(ctl + Z0CNT, 128u * (u32)(s + 1));
      __syncthreads();
      gemv_dirz<4, 8>(wC, g_.z0f8, L, tid);
      __syncthreads();
      if (s < cNS - 1){
        const int jb = (blk - 192) * 32;
        int bb = tid >> 4, j2 = (tid & 15) * 2;
        int mt = bb >> 4, rr = bb & 15;
        #pragma unroll
        for (int k = 0; k < 2; ++k){
          int jj = j2 + k;
          float v = 0.f;
          #pragma unroll
          for (int kh = 0; kh < 4; ++kh)
            v += L.gv.acc[(jj >> 4) * 4 + kh][mt][rr][jj & 15];
          st_sc(&g_.q[bb * cA + jb + jj], v * DS);
        }
      }
      __syncthreads();
      if (tid == 0) inc8(ctl + QCNT, blk);
    } else if (blk == 208){
      if (tid == 0)
        gate8(ctl + SCNT + p * 128, 128u * ((u32)(s >> 1) + 1u));
      __syncthreads();
      {
        float* aa = g_.att_acc + (size_t)p * cB * cE;
        for (int i = tid; i < cB * cE; i += 512) st_sc(&aa[i], 0.f);
        if (tid < cB) st_sc(&g_.att_l[p * cB + tid], 0.f);
      }
      __syncthreads();
      if (tid == 0){
        asm volatile("s_waitcnt vmcnt(0)" ::: "memory");
        st_su(&ctl[ZDONE + p * 16], (u32)(s >> 1) + 1u);
      }
    }
  }
}

// ------------------------------ epilogue -----------------------------------
__global__ __launch_bounds__(256) void k_ce1(const u16* __restrict__ z1all,
    const u16* __restrict__ Woutb, const float* __restrict__ bout,
    const int* __restrict__ ys, float* __restrict__ pmax, float* __restrict__ psum,
    int* __restrict__ pai, float* __restrict__ tgtl){
  int blk = blockIdx.x;
  int sc = blk / 40, vc = blk % 40;
  int tid = threadIdx.x, w = tid >> 6, l = tid & 63;
  int kin = 8 * (l >> 4), col = l & 15;
  int v0 = vc * 128 + w * 32;
  int vA = v0 + col, vB = v0 + 16 + col;
  float boA = (vA < cV) ? bout[vA] : 0.f;
  float boB = (vB < cV) ? bout[vB] : 0.f;
  const u16* wrA = Woutb + (size_t)((vA < cV) ? vA : cV - 1) * cD;
  const u16* wrB = Woutb + (size_t)((vB < cV) ? vB : cV - 1) * cD;
  __shared__ int tgt_sh[32];
  __shared__ float rsm[4][32], rss[4][32];
  __shared__ int rsi[4][32];
  for (int si = 0; si < 5; ++si){
    int s = sc * 5 + si;
    if (tid < 32) tgt_sh[tid] = (s < cL) ? ys[tid * cL + s] : EOS;
    __syncthreads();
    const u16* z1s = z1all + ((size_t)s + 1) * cB * cD;
    f32x4 aA0 = {0.f,0.f,0.f,0.f}, aA1 = {0.f,0.f,0.f,0.f};
    f32x4 aB0 = {0.f,0.f,0.f,0.f}, aB1 = {0.f,0.f,0.f,0.f};
    for (int kc = 0; kc < 32; ++kc){
      int k = kc * 32 + kin;
      s16x8 x0 = LD8(z1s + (size_t)col * cD + k);
      s16x8 x1 = LD8(z1s + (size_t)(16 + col) * cD + k);
      s16x8 bA = LD8(wrA + k);
      s16x8 bB = LD8(wrB + k);
      aA0 = MFMA(x0, bA, aA0); aA1 = MFMA(x1, bA, aA1);
      aB0 = MFMA(x0, bB, aB0); aB1 = MFMA(x1, bB, aB1);
    }
    #pragma unroll
    for (int mt = 0; mt < 2; ++mt)
    #pragma unroll
    for (int reg = 0; reg < 4; ++reg){
      int row = mt * 16 + (l >> 4) * 4 + reg;
      float va = (mt ? aA1[reg] : aA0[reg]) + boA; if (vA >= cV) va = -1e30f;
      float vb = (mt ? aB1[reg] : aB0[reg]) + boB; if (vB >= cV) vb = -1e30f;
      int tg = tgt_sh[row];
      if (vA == tg) tgtl[(size_t)s * cB + row] = va;
      if (vB == tg) tgtl[(size_t)s * cB + row] = vb;
      float mx = fmaxf(va, vb);
      int ix = (va >= vb) ? vA : vB;
      #pragma unroll
      for (int m = 1; m < 16; m <<= 1){
        float om = __shfl_xor(mx, m, 64);
        int oi = __shfl_xor(ix, m, 64);
        if (om > mx || (om == mx && oi < ix)){ mx = om; ix = oi; }
      }
      float se = __expf(va - mx) + __expf(vb - mx);
      #pragma unroll
      for (int m = 1; m < 16; m <<= 1) se += __shfl_xor(se, m, 64);
      if ((l & 15) == 0){ rsm[w][row] = mx; rss[w][row] = se; rsi[w][row] = ix; }
    }
    __syncthreads();
    if (tid < 32){
      int b = tid;
      float gm = -1e30f;
      #pragma unroll
      for (int w2 = 0; w2 < 4; ++w2) gm = fmaxf(gm, rsm[w2][b]);
      float gs = 0.f; float bv = -1e30f; int bix = 0x7fffffff;
      #pragma unroll
      for (int w2 = 0; w2 < 4; ++w2){
        gs += rss[w2][b] * __expf(rsm[w2][b] - gm);
        float v = rsm[w2][b]; int ii = rsi[w2][b];
        if (v > bv || (v == bv && ii < bix)){ bv = v; bix = ii; }
      }
      size_t o = ((size_t)s * cB + b) * 40 + vc;
      pmax[o] = gm; psum[o] = gs; pai[o] = bix;
    }
    __syncthreads();
  }
}

__global__ __launch_bounds__(64) void k_ce2(const float* __restrict__ pmax,
    const float* __restrict__ psum, const int* __restrict__ pai,
    const float* __restrict__ tgtl, const int* __restrict__ ys,
    float* __restrict__ cestep){
  int s = blockIdx.x, tid = threadIdx.x;
  float nll = 0.f, cor = 0.f;
  if (tid < 32){
    int b = tid;
    size_t o = ((size_t)s * cB + b) * 40;
    float gm = -1e30f;
    for (int c = 0; c < 40; ++c) gm = fmaxf(gm, pmax[o + c]);
    float gs = 0.f; float bv = -1e30f; int bix = 0x7fffffff;
    for (int c = 0; c < 40; ++c){
      gs += psum[o + c] * __expf(pmax[o + c] - gm);
      float v = pmax[o + c]; int ii = pai[o + c];
      if (v > bv || (v == bv && ii < bix)){ bv = v; bix = ii; }
    }
    nll = __logf(gs) + gm - tgtl[(size_t)s * cB + b];
    int tgt = (s < cL) ? ys[b * cL + s] : EOS;
    cor = (bix == tgt) ? 1.f : 0.f;
  }
  #pragma unroll
  for (int m = 1; m < 64; m <<= 1){
    nll += __shfl_xor(nll, m, 64); cor += __shfl_xor(cor, m, 64);
  }
  if (tid == 0){ cestep[s * 2] = nll; cestep[s * 2 + 1] = cor; }
}

__global__ __launch_bounds__(256) void k_ce3(const float* __restrict__ cestep,
                                             float* __restrict__ out){
  int tid = threadIdx.x;
  float nll = 0.f, cor = 0.f;
  for (int s = tid; s < cNS; s += 256){ nll += cestep[s * 2]; cor += cestep[s * 2 + 1]; }
  __shared__ float sn[4], sc_[4];
  int w = tid >> 6, l = tid & 63;
  #pragma unroll
  for (int m = 1; m < 64; m <<= 1){
    nll += __shfl_xor(nll, m, 64); cor += __shfl_xor(cor, m, 64);
  }
  if (l == 0){ sn[w] = nll; sc_[w] = cor; }
  __syncthreads();
  if (tid == 0){
    float a = sn[0] + sn[1] + sn[2] + sn[3];
    float b = sc_[0] + sc_[1] + sc_[2] + sc_[3];
    out[0] = a / (float)(cB * cNS) * (float)cL;
    out[1] = b / (float)(cB * cNS);
  }
}

// ------------------------------- host --------------------------------------
extern "C" void kernel_launch(void* const* d_in, const int* in_sizes, int n_in,
                              void* d_out, int out_size, void* d_ws, size_t ws_size,
                              hipStream_t stream){
  const float* hpad = (const float*)d_in[0];
  const int*   hlen = (const int*)d_in[1];
  const int*   ys   = (const int*)d_in[2];
  const float* embed= (const float*)d_in[3];
  const float* Wout = (const float*)d_in[4];
  const float* bout = (const float*)d_in[5];
  const float* Wenc = (const float*)d_in[6];
  const float* Wdec = (const float*)d_in[7];
  const float* vatt = (const float*)d_in[8];
  const float* Wih0 = (const float*)d_in[9];
  const float* bih0 = (const float*)d_in[10];
  const float* Whh0 = (const float*)d_in[11];
  const float* bhh0 = (const float*)d_in[12];
  const float* Wih1 = (const float*)d_in[13];
  const float* bih1 = (const float*)d_in[14];
  const float* Whh1 = (const float*)d_in[15];
  const float* bhh1 = (const float*)d_in[16];
  (void)in_sizes; (void)n_in; (void)out_size; (void)ws_size;

  char* base = (char*)d_ws;
  size_t off = 0;
  auto alloc = [&](size_t bytes) -> void* {
    void* r = base + off; off += (bytes + 255) & ~(size_t)255; return r;
  };
  u32*   ctl     = (u32*)  alloc(1152 * 4);
  u16*   hpadM   = (u16*)  alloc((size_t)cB * cT * cE * 2);
  u8*    ph8     = (u8*)   alloc((size_t)cB * cT * 1024);
  u16*   embb    = (u16*)  alloc((size_t)cV * cD * 2);
  u16*   ey      = (u16*)  alloc((size_t)cNS * cB * cD * 2);
  u16*   eyproj  = (u16*)  alloc((size_t)cNS * cB * 4096 * 2);
  u16*   z1all   = (u16*)  alloc((size_t)(cNS + 1) * cB * cD * 2);
  u16*   WencT   = (u16*)  alloc((size_t)cA * cE * 2);
  u16*   Wih0m   = (u16*)  alloc((size_t)4096 * cD * 2);
  u16*   Woutb   = (u16*)  alloc((size_t)cV * cD * 2);
  u8*    Wapf8   = (u8*)   alloc((size_t)4096 * 512);
  u8*    Wih1f8  = (u8*)   alloc((size_t)4096 * 1024);
  u8*    Whh1f8  = (u8*)   alloc((size_t)4096 * 1024);
  u8*    Whh0f8  = (u8*)   alloc((size_t)4096 * 1024);
  u8*    WdecTf8 = (u8*)   alloc((size_t)512 * 1024);
  float* bias01  = (float*)alloc(4096 * 4);
  float* qbuf    = (float*)alloc((size_t)cB * cA * 4);
  float* att_acc = (float*)alloc((size_t)2 * cB * cE * 4);
  float* att_l   = (float*)alloc((size_t)2 * cB * 4);
  float* g0buf   = (float*)alloc((size_t)2 * cB * 4096 * 4);
  float* hh1buf  = (float*)alloc((size_t)cB * 4096 * 4);
  u8*    z0f8    = (u8*)   alloc((size_t)cB * cD);
  u8*    z1f8    = (u8*)   alloc((size_t)cB * cD);
  float* c0      = (float*)alloc((size_t)2 * cB * cD * 4);
  float* c1      = (float*)alloc((size_t)2 * cB * cD * 4);
  float* pmax    = (float*)alloc((size_t)cNS * cB * 40 * 4);
  float* psum    = (float*)alloc((size_t)cNS * cB * 40 * 4);
  int*   pai     = (int*)  alloc((size_t)cNS * cB * 40 * 4);
  float* tgtl    = (float*)alloc((size_t)cNS * cB * 4);
  float* cestep  = (float*)alloc((size_t)cNS * 2 * 4);

  k_init<<<64, 256, 0, stream>>>(ctl, qbuf, c0, c1, z1f8, att_acc, att_l);
  k_cvt<<<2048, 256, 0, stream>>>(hpad, hpadM, cB * cT * cE / 4);
  k_cvt8I<<<1024, 256, 0, stream>>>(hpad, ph8, cB * cT * 64);
  k_cvt<<<2048, 256, 0, stream>>>(embed, embb, cV * cD / 4);
  k_cvt<<<2048, 256, 0, stream>>>(Wout, Woutb, cV * cD / 4);
  k_slice<<<1024, 256, 0, stream>>>(Wih0, Wih0m, 4096 * cD, 10, 1536, 0);
  k_transp<<<256, 256, 0, stream>>>(Wenc, WencT, cA * cE, 9, cA);
  k_bias<<<16, 256, 0, stream>>>(bih1, bhh1, bias01, 4096);
  k_wf8perm<<<512, 256, 0, stream>>>(Wih0, Wapf8, 4096 * 512 / 4, 9, 1536, 1024);
  k_wf8perm<<<1024, 256, 0, stream>>>(Wih1, Wih1f8, 4096 * 1024 / 4, 10, 1024, 0);
  k_wf8<<<1024, 256, 0, stream>>>(Whh1, Whh1f8, 4096 * 1024 / 4);
  k_wf8<<<1024, 256, 0, stream>>>(Whh0, Whh0f8, 4096 * 1024 / 4);
  k_wf8t<<<128, 256, 0, stream>>>(Wdec, WdecTf8, 512 * 1024 / 4);
  k_gather<<<1200, 256, 0, stream>>>(embb, ys, ey, cNS * cB * 128);
  k_pe2<<<200, 512, 0, stream>>>(hpadM, WencT, ph8);
  k_ey2<<<dim3(38, 8), 512, 0, stream>>>(ey, Wih0m, bih0, bhh0, eyproj, g0buf);

  LoopArgs la;
  la.hlen = hlen; la.ph8 = ph8; la.eyproj = eyproj;
  la.Wapf8 = Wapf8; la.Whh1f8 = Whh1f8; la.Wih1f8 = Wih1f8;
  la.Whh0f8 = Whh0f8; la.WdecTf8 = WdecTf8;
  la.vatt = vatt; la.bias01 = bias01;
  la.q = qbuf; la.att_acc = att_acc; la.att_l = att_l;
  la.g0buf = g0buf; la.hh1buf = hh1buf; la.z0f8 = z0f8; la.z1f8 = z1f8;
  la.c0 = c0; la.c1 = c1; la.z1all = z1all; la.ctl = ctl;
  k_loop<<<NBLK, 512, 0, stream>>>(la);

  k_ce1<<<1200, 256, 0, stream>>>(z1all, Woutb, bout, ys, pmax, psum, pai, tgtl);
  k_ce2<<<cNS, 64, 0, stream>>>(pmax, psum, pai, tgtl, ys, cestep);
  k_ce3<<<1, 256, 0, stream>>>(cestep, (float*)d_out);
}

// Round 8
// 4852.106 us; speedup vs baseline: 1.6614x; 1.1792x over previous
//
#include <hip/hip_runtime.h>

// ---------------------------------------------------------------------------
// Decoder_60868276519063: attention-LSTM decoder forward (loss, acc)
// B=32 T=800 E=512 D=1024 V=5000 L=149 (150 steps) A=512
// Round 8: r5 compute structure (LDS-staged fp8 MFMA GEMVs, register-resident
// weights, LDS-resident attention, fence-free sc1 data movement) + store-based
// per-producer flags with direct consumer polling (no RMW counters, no
// collector, no barriers). Critical cycle A->LSTM0->Wdec->q pipelines with
// one L3 hop per handoff; hh1/g0/zeroing run overlapped off-cycle.
// ---------------------------------------------------------------------------

typedef unsigned short u16;
typedef unsigned char u8;
typedef unsigned int u32;
typedef long long i64;
typedef unsigned long long u64;
typedef float f32x4 __attribute__((ext_vector_type(4)));
typedef float f32x2 __attribute__((ext_vector_type(2)));
typedef short s16x8 __attribute__((ext_vector_type(8)));

constexpr int cB = 32, cT = 800, cE = 512, cD = 1024, cV = 5000, cL = 149,
              cNS = 150, cA = 512;
constexpr int SOS = 1, EOS = 2;
constexpr int NBLK = 256;
constexpr float DS = 1.0f / 128.0f;   // fp8 descale: W x16, x x8

// flag indices into ctl[] (u32 units); store-based, one word per producer
constexpr int AFLAG = 0;       // 256: A-phase done (atomic adds drained)
constexpr int Z0FLAG = 256;    // 128: z0(s) ready  (value s+1)
constexpr int HH1FLAG = 384;   // 128: hh1(s) ready (value s+1)
constexpr int Z1FLAG = 512;    // 128: z1(s) ready  (value s+1)
constexpr int G0FLAG = 640;    //  64: g0(s+1) ready (value s+1)
constexpr int QFLAG = 704;     //  16: q(s+1) ready  (value s+1)  [1 cache line]
constexpr int SFLAG = 720;     // +p*128, 128: att parity consumed (value (s>>1)+1)
constexpr int ZDONEW = 976;    // +p*16: att parity re-zeroed (value (s>>1)+1)

__device__ __forceinline__ float bf2f(u16 x){
  union { u32 u; float f; } v; v.u = ((u32)x) << 16; return v.f;
}
__device__ __forceinline__ u16 f2bf(float f){
  union { float f; u32 u; } v; v.f = f;
  u32 r = v.u + 0x7FFFu + ((v.u >> 16) & 1u);
  return (u16)(r >> 16);
}
__device__ __forceinline__ float frcp(float x){ return __builtin_amdgcn_rcpf(x); }
__device__ __forceinline__ float fsigm(float x){ return frcp(1.f + __expf(-x)); }
__device__ __forceinline__ float ftanh(float x){
  float u = __expf(2.f * x);
  return 1.f - 2.f * frcp(u + 1.f);
}
__device__ __forceinline__ f32x4 MFMA(s16x8 a, s16x8 b, f32x4 c){
  return __builtin_amdgcn_mfma_f32_16x16x32_bf16(a, b, c, 0, 0, 0);
}
__device__ __forceinline__ f32x4 MFMA8(i64 a, i64 b, f32x4 c){
  return __builtin_amdgcn_mfma_f32_16x16x32_fp8_fp8(a, b, c, 0, 0, 0);
}
__device__ __forceinline__ s16x8 LD8(const u16* p){ return *(const s16x8*)p; }
__device__ __forceinline__ u8 f2fp8(float x){
  return (u8)(__builtin_amdgcn_cvt_pk_fp8_f32(x, x, 0, false) & 0xFF);
}
__device__ __forceinline__ u32 pk4(float a, float b, float c, float d){
  u32 w = (u32)__builtin_amdgcn_cvt_pk_fp8_f32(a, b, 0, false);
  w = (u32)__builtin_amdgcn_cvt_pk_fp8_f32(c, d, (int)w, true);
  return w;
}
__device__ __forceinline__ void unpack8(u32 lo, u32 hi, float* o){
  f32x2 a = __builtin_amdgcn_cvt_pk_f32_fp8((int)lo, false);
  f32x2 b = __builtin_amdgcn_cvt_pk_f32_fp8((int)lo, true);
  f32x2 c = __builtin_amdgcn_cvt_pk_f32_fp8((int)hi, false);
  f32x2 d = __builtin_amdgcn_cvt_pk_f32_fp8((int)hi, true);
  o[0]=a[0]; o[1]=a[1]; o[2]=b[0]; o[3]=b[1];
  o[4]=c[0]; o[5]=c[1]; o[6]=d[0]; o[7]=d[1];
}

// ---- agent-scope (sc1) relaxed accessors (coherent at L3, no fences) ------
__device__ __forceinline__ float ld_sc(const float* p){
  return __hip_atomic_load(p, __ATOMIC_RELAXED, __HIP_MEMORY_SCOPE_AGENT);
}
__device__ __forceinline__ void st_sc(float* p, float v){
  __hip_atomic_store(p, v, __ATOMIC_RELAXED, __HIP_MEMORY_SCOPE_AGENT);
}
__device__ __forceinline__ u64 ld_sc8(const void* p){
  return __hip_atomic_load((const u64*)p, __ATOMIC_RELAXED, __HIP_MEMORY_SCOPE_AGENT);
}
__device__ __forceinline__ u32 ld_su(const u32* p){
  return __hip_atomic_load(p, __ATOMIC_RELAXED, __HIP_MEMORY_SCOPE_AGENT);
}
__device__ __forceinline__ void st_su(u32* p, u32 v){
  __hip_atomic_store(p, v, __ATOMIC_RELAXED, __HIP_MEMORY_SCOPE_AGENT);
}
__device__ __forceinline__ void st_scb(u8* p, u8 v){
  __hip_atomic_store(p, v, __ATOMIC_RELAXED, __HIP_MEMORY_SCOPE_AGENT);
}

// poll n flag words (store-based, monotone) until all >= target; call from
// wave 0 only, follow with __syncthreads()
__device__ __forceinline__ void pollge(const u32* f, int n, u32 target){
  const int lane = threadIdx.x & 63;
  for(;;){
    bool ok = true;
    for (int i = lane; i < n; i += 64) ok &= (ld_su(f + i) >= target);
    if (__all(ok)) break;
    __builtin_amdgcn_s_sleep(1);
  }
}
// signal: preceding __syncthreads drained all waves' vmcnt; extra drain cheap
__device__ __forceinline__ void sig(u32* f, u32 v){
  asm volatile("s_waitcnt vmcnt(0)" ::: "memory");
  st_su(f, v);
}

// ------------------------------- prologue ----------------------------------
__global__ void k_init(u32* ctl, float* q, float* c0, float* c1, u8* z1f8,
                       float* att_acc, float* att_l){
  int i = blockIdx.x * blockDim.x + threadIdx.x, n = gridDim.x * blockDim.x;
  for (int k = i; k < 1024; k += n) ctl[k] = 0;
  for (int k = i; k < cB * cA; k += n) q[k] = 0.f;
  for (int k = i; k < 2 * cB * cD; k += n){ c0[k] = 0.f; c1[k] = 0.f; }
  for (int k = i; k < cB * cD / 4; k += n) ((u32*)z1f8)[k] = 0;
  for (int k = i; k < 2 * cB * cE; k += n) att_acc[k] = 0.f;
  for (int k = i; k < 2 * cB; k += n) att_l[k] = 0.f;
}

__global__ void k_cvt(const float* __restrict__ s, u16* __restrict__ d, int n4){
  int i = blockIdx.x * blockDim.x + threadIdx.x, st = gridDim.x * blockDim.x;
  for (int k = i; k < n4; k += st){
    float4 v = ((const float4*)s)[k];
    ushort4 o; o.x = f2bf(v.x); o.y = f2bf(v.y); o.z = f2bf(v.z); o.w = f2bf(v.w);
    ((ushort4*)d)[k] = o;
  }
}

// hpad -> fp8 h-half of interleaved ph8 rows: [grp*16+8 .. +15]
__global__ void k_cvt8I(const float* __restrict__ s, u8* __restrict__ d, int n){
  int i = blockIdx.x * blockDim.x + threadIdx.x, st = gridDim.x * blockDim.x;
  for (int k = i; k < n; k += st){
    int row = k >> 6, grp = k & 63;
    const float4* p = (const float4*)(s + (size_t)row * 512 + grp * 8);
    float4 v0 = p[0], v1 = p[1];
    u32 lo = pk4(v0.x, v0.y, v0.z, v0.w);
    u32 hi = pk4(v1.x, v1.y, v1.z, v1.w);
    *(uint2*)(d + (size_t)row * 1024 + grp * 16 + 8) = make_uint2(lo, hi);
  }
}

__global__ void k_slice(const float* __restrict__ s, u16* __restrict__ d, int n,
                        int cshift, int srcld, int coff){
  int i = blockIdx.x * blockDim.x + threadIdx.x, st = gridDim.x * blockDim.x;
  int cmask = (1 << cshift) - 1;
  for (int k = i; k < n; k += st){
    int r = k >> cshift, c = k & cmask;
    d[k] = f2bf(s[(size_t)r * srcld + coff + c]);
  }
}

__global__ void k_transp(const float* __restrict__ s, u16* __restrict__ d, int n,
                         int rshift, int csrc){
  int i = blockIdx.x * blockDim.x + threadIdx.x, st = gridDim.x * blockDim.x;
  int mask = (1 << rshift) - 1;
  for (int k = i; k < n; k += st){
    int dd = k & mask, a = k >> rshift;
    d[k] = f2bf(s[(size_t)dd * csrc + a]);
  }
}

__global__ void k_bias(const float* a, const float* b, float* o, int n){
  int i = blockIdx.x * blockDim.x + threadIdx.x, st = gridDim.x * blockDim.x;
  for (int k = i; k < n; k += st) o[k] = a[k] + b[k];
}

// fp8 weight convert, x16 scale, row-permuted: dst row R=j*32+jj, jj=g*8+c
__global__ void k_wf8perm(const float* __restrict__ s, u8* __restrict__ d,
                          int n4, int kshift, int srcld, int coff){
  int i = blockIdx.x * blockDim.x + threadIdx.x, st = gridDim.x * blockDim.x;
  int kmask = (1 << kshift) - 1;
  for (int k = i; k < n4; k += st){
    int flat = k * 4;
    int R = flat >> kshift, kk = flat & kmask;
    int j = R >> 5, jj = R & 31, g = jj >> 3, c = jj & 7;
    const float* p = s + (size_t)(g * 1024 + j * 8 + c) * srcld + coff + kk;
    ((u32*)d)[k] = pk4(p[0]*16.f, p[1]*16.f, p[2]*16.f, p[3]*16.f);
  }
}

__global__ void k_wf8(const float* __restrict__ s, u8* __restrict__ d, int n4){
  int i = blockIdx.x * blockDim.x + threadIdx.x, st = gridDim.x * blockDim.x;
  for (int k = i; k < n4; k += st){
    float4 v = ((const float4*)s)[k];
    ((u32*)d)[k] = pk4(v.x*16.f, v.y*16.f, v.z*16.f, v.w*16.f);
  }
}

// WdecT fp8: dst[a][dd] = Wdec[dd][a] * 16, dst [512][1024]
__global__ void k_wf8t(const float* __restrict__ s, u8* __restrict__ d, int n4){
  int i = blockIdx.x * blockDim.x + threadIdx.x, st = gridDim.x * blockDim.x;
  for (int k = i; k < n4; k += st){
    int flat = k * 4;
    int a = flat >> 10, dd = flat & 1023;
    ((u32*)d)[k] = pk4(s[(size_t)(dd+0)*512 + a]*16.f,
                       s[(size_t)(dd+1)*512 + a]*16.f,
                       s[(size_t)(dd+2)*512 + a]*16.f,
                       s[(size_t)(dd+3)*512 + a]*16.f);
  }
}

// ey[r][:] = embb[tok(r)][:]  (bf16 gather), r = s*32+b
__global__ void k_gather(const u16* __restrict__ embb, const int* __restrict__ ys,
                         u16* __restrict__ ey, int n16){
  int i = blockIdx.x * blockDim.x + threadIdx.x, st = gridDim.x * blockDim.x;
  for (int k = i; k < n16; k += st){
    int r = k >> 7, seg = k & 127;
    int s = r >> 5, b = r & 31;
    int tok = (s == 0) ? SOS : ys[b * cL + (s - 1)];
    ((uint4*)ey)[(size_t)r * 128 + seg] =
        ((const uint4*)embb)[(size_t)tok * 128 + seg];
  }
}

// pe GEMM: [25600x512] @ WencT[512 a][512 e]^T -> fp8 into ph8 pe-half
__global__ __launch_bounds__(512, 1) void k_pe2(const u16* __restrict__ A,
    const u16* __restrict__ Bw, u8* __restrict__ ph8){
  int tid = threadIdx.x, w = tid >> 6, l = tid & 63;
  int col = l & 15, kin = 8 * (l >> 4);
  int mw = w >> 2, nw = w & 3;
  int m0 = blockIdx.x * 128 + mw * 64;
  int n0 = nw * 128;
  f32x4 acc[4][8] = {};
  for (int kc = 0; kc < 16; ++kc){
    int k = kc * 32 + kin;
    s16x8 af[4], bf[8];
    #pragma unroll
    for (int i = 0; i < 4; ++i) af[i] = LD8(A + (size_t)(m0 + i*16 + col)*512 + k);
    #pragma unroll
    for (int j = 0; j < 8; ++j) bf[j] = LD8(Bw + (size_t)(n0 + j*16 + col)*512 + k);
    #pragma unroll
    for (int i = 0; i < 4; ++i)
      #pragma unroll
      for (int j = 0; j < 8; ++j) acc[i][j] = MFMA(af[i], bf[j], acc[i][j]);
  }
  int hi4 = (l >> 4) * 4;
  #pragma unroll
  for (int i = 0; i < 4; ++i)
    #pragma unroll
    for (int j = 0; j < 8; ++j){
      int a0 = n0 + j * 16 + col;
      size_t boff = ((size_t)(a0 >> 3) << 4) + (a0 & 7);
      #pragma unroll
      for (int r = 0; r < 4; ++r){
        int row = m0 + i * 16 + hi4 + r;
        ph8[(size_t)row * 1024 + boff] = f2fp8(acc[i][j][r]);
      }
    }
}

// eyproj GEMM: ey[4800x1024] @ Wih0m[4096x1024]^T + biases -> bf16 (+g0 f32)
__global__ __launch_bounds__(512, 1) void k_ey2(const u16* __restrict__ ey,
    const u16* __restrict__ Wm, const float* __restrict__ bih0,
    const float* __restrict__ bhh0, u16* __restrict__ eyproj,
    float* __restrict__ g0buf){
  int tid = threadIdx.x, w = tid >> 6, l = tid & 63;
  int col = l & 15, kin = 8 * (l >> 4);
  int mw = w >> 2, nw = w & 3;
  int m0 = blockIdx.x * 128 + mw * 64;
  int n0 = blockIdx.y * 512 + nw * 128;
  f32x4 acc[4][8] = {};
  for (int kc = 0; kc < 32; ++kc){
    int k = kc * 32 + kin;
    s16x8 af[4], bf[8];
    #pragma unroll
    for (int i = 0; i < 4; ++i){
      int ar = m0 + i * 16 + col; ar = (ar < 4800) ? ar : 0;
      af[i] = LD8(ey + (size_t)ar * 1024 + k);
    }
    #pragma unroll
    for (int j = 0; j < 8; ++j) bf[j] = LD8(Wm + (size_t)(n0 + j*16 + col)*1024 + k);
    #pragma unroll
    for (int i = 0; i < 4; ++i)
      #pragma unroll
      for (int j = 0; j < 8; ++j) acc[i][j] = MFMA(af[i], bf[j], acc[i][j]);
  }
  int hi4 = (l >> 4) * 4;
  #pragma unroll
  for (int i = 0; i < 4; ++i)
    #pragma unroll
    for (int j = 0; j < 8; ++j){
      int jc = n0 + j * 16 + col;
      float bj = bih0[jc] + bhh0[jc];
      #pragma unroll
      for (int r = 0; r < 4; ++r){
        int row = m0 + i * 16 + hi4 + r;
        if (row < 4800){
          float val = acc[i][j][r] + bj;
          eyproj[(size_t)row * 4096 + jc] = f2bf(val);
          if (row < 32) g0buf[(size_t)row * 4096 + jc] = val;  // parity-0 slot
        }
      }
    }
}

// ------------------------------ main loop ----------------------------------
struct LoopArgs {
  const int* hlen;
  const u8* ph8;
  const u16* eyproj;
  const u8* Wapf8; const u8* Whh1f8; const u8* Wih1f8; const u8* Whh0f8;
  const u8* WdecTf8;
  const float* vatt; const float* bias01;
  float* q; float* att_acc; float* att_l;
  float* g0buf; float* hh1buf; u8* z0f8; u8* z1f8;
  float* c0; float* c1; u16* z1all;
  u32* ctl;
};

// LDS x row strides (bytes)
constexpr int SPZ = 1048;   // K=1024 rows
constexpr int SPA = 536;    // K=512 rows

struct P1Lds { float red[8][512]; float ls[8]; };
struct GvLds { u8 x[32 * SPZ]; float acc[8][2][16][17]; };
union LoopLds { P1Lds p1; GvLds gv; };

// stage att_acc (sc1 f32, normalize by att_l, x8) -> fp8 LDS x[32][512]
__device__ __forceinline__ void stage_att(LoopLds& L, const float* att_acc,
                                          const float* att_l, int tid){
  int r = tid >> 4, c0 = (tid & 15) * 32;
  float sc = 8.0f * frcp(ld_sc(att_l + r));
  const float* src = att_acc + r * 512 + c0;
  u32 wd[8];
  #pragma unroll
  for (int i = 0; i < 8; ++i){
    union { u64 q; float f[2]; } a, b;
    a.q = ld_sc8(src + i * 4);
    b.q = ld_sc8(src + i * 4 + 2);
    wd[i] = pk4(a.f[0] * sc, a.f[1] * sc, b.f[0] * sc, b.f[1] * sc);
  }
  uint2* dst = (uint2*)&L.gv.x[r * SPA + c0];
  dst[0] = make_uint2(wd[0], wd[1]);
  dst[1] = make_uint2(wd[2], wd[3]);
  dst[2] = make_uint2(wd[4], wd[5]);
  dst[3] = make_uint2(wd[6], wd[7]);
}

// stage fp8 z[32][1024] (sc1) -> LDS x, SP=SPZ
__device__ __forceinline__ void stage_z(LoopLds& L, const u8* zf8, int tid){
  int r = tid >> 4, c0 = (tid & 15) * 64;
  const u8* src = zf8 + (size_t)r * 1024 + c0;
  u64 v[8];
  #pragma unroll
  for (int i = 0; i < 8; ++i) v[i] = ld_sc8(src + i * 8);
  u64* dst = (u64*)&L.gv.x[r * SPZ + c0];
  #pragma unroll
  for (int i = 0; i < 8; ++i) dst[i] = v[i];
}

// block GEMV from register-resident weights: wave w: nt = w/KH, kh = w%KH.
template<int KH, int ITERS, int SP>
__device__ __forceinline__ void gemv_reg(const i64* wreg, LoopLds& L, int tid){
  const int w = tid >> 6, l = tid & 63;
  const int col = l & 15, kin = 8 * (l >> 4);
  const int kh = (KH == 4) ? (w & 3) : (w & 1);
  constexpr int KB = ITERS * 32;
  const u8* xr = &L.gv.x[col * SP + kh * KB + kin];
  f32x4 a0 = {0.f,0.f,0.f,0.f}, a1 = {0.f,0.f,0.f,0.f};
  #pragma unroll
  for (int kc = 0; kc < ITERS; ++kc){
    i64 x0 = *(const i64*)(xr + kc * 32);
    i64 x1 = *(const i64*)(xr + 16 * SP + kc * 32);
    a0 = MFMA8(x0, wreg[kc], a0);
    a1 = MFMA8(x1, wreg[kc], a1);
  }
  const int hi4 = (l >> 4) * 4;
  #pragma unroll
  for (int r = 0; r < 4; ++r){
    L.gv.acc[w][0][hi4 + r][col] = a0[r];
    L.gv.acc[w][1][hi4 + r][col] = a1[r];
  }
}

__global__ __launch_bounds__(512, 1) void k_loop(LoopArgs g_){
  __shared__ __align__(16) LoopLds L;
  __shared__ __align__(16) u8 ph8_lds[100 * 1024];
  const int blk = blockIdx.x, tid = threadIdx.x;
  const int w = tid >> 6, l = tid & 63;
  const int col = l & 15, kin = 8 * (l >> 4);
  const int b_att = blk >> 3, oct = blk & 7;
  const int hl = g_.hlen[b_att];
  const int t0 = oct * 100;
  const int t1 = (t0 + 100 < hl) ? t0 + 100 : hl;
  const int nrow = t1 - t0;
  u32* ctl = g_.ctl;
  float vv[8];
  #pragma unroll
  for (int i = 0; i < 8; ++i) vv[i] = g_.vatt[l * 8 + i];
  for (int idx = tid; idx < nrow * 64; idx += 512){
    int rr = idx >> 6, gg = idx & 63;
    *(uint4*)&ph8_lds[rr * 1024 + gg * 16] =
        *(const uint4*)(g_.ph8 + ((size_t)b_att * cT + t0 + rr) * 1024 + gg * 16);
  }
  // ---- preload step-invariant weight fragments into registers ----
  i64 wB[8], wC[16];
  {
    const int nt4 = w >> 2, kh4 = w & 3;
    const int nt2 = w >> 1, kh2 = w & 1;
    if (blk < 128){
      const u8* wr = g_.Wapf8 + (size_t)blk * 32 * 512 +
                     (size_t)(nt4 * 16 + col) * 512 + kh4 * 128 + kin;
      #pragma unroll
      for (int kc = 0; kc < 4; ++kc) wB[kc] = *(const i64*)(wr + kc * 32);
      const u8* wr2 = g_.Wih1f8 + (size_t)blk * 32 * 1024 +
                      (size_t)(nt4 * 16 + col) * 1024 + kh4 * 256 + kin;
      #pragma unroll
      for (int kc = 0; kc < 8; ++kc) wC[kc] = *(const i64*)(wr2 + kc * 32);
    } else {
      const u8* wr = g_.Whh1f8 + (size_t)(blk - 128) * 32 * 1024 +
                     (size_t)(nt4 * 16 + col) * 1024 + kh4 * 256 + kin;
      #pragma unroll
      for (int kc = 0; kc < 8; ++kc) wB[kc] = *(const i64*)(wr + kc * 32);
      if (blk < 192){
        const u8* wr2 = g_.Whh0f8 + (size_t)(blk - 128) * 64 * 1024 +
                        (size_t)(nt2 * 16 + col) * 1024 + kh2 * 512 + kin;
        #pragma unroll
        for (int kc = 0; kc < 16; ++kc) wC[kc] = *(const i64*)(wr2 + kc * 32);
      } else if (blk < 208){
        const u8* wr2 = g_.WdecTf8 + (size_t)(blk - 192) * 32 * 1024 +
                        (size_t)(nt4 * 16 + col) * 1024 + kh4 * 256 + kin;
        #pragma unroll
        for (int kc = 0; kc < 8; ++kc) wC[kc] = *(const i64*)(wr2 + kc * 32);
      }
    }
  }
  __syncthreads();

  for (int s = 0; s < cNS; ++s){
    const int p = s & 1;
    // ================= A: attention ======================================
    if (nrow > 0){
      if (tid < 64){
        pollge(ctl + QFLAG, 16, (u32)s);             // q(s) ready
        if (tid == 0){
          u32 need = (u32)(s >> 1);                  // att_acc[p] re-zeroed
          while (ld_su(&ctl[ZDONEW + p * 16]) < need)
            __builtin_amdgcn_s_sleep(1);
        }
      }
      __syncthreads();
      float qv[8];
      const float* qb = g_.q + b_att * cA + l * 8;
      #pragma unroll
      for (int i = 0; i < 8; ++i) qv[i] = ld_sc(qb + i);
      float acc8[8] = {0.f,0.f,0.f,0.f,0.f,0.f,0.f,0.f};
      float lsum = 0.f;
      for (int t = t0 + w; t < t1; t += 8){
        uint4 v = *(const uint4*)&ph8_lds[(t - t0) * 1024 + l * 16];
        float x[8]; unpack8(v.x, v.y, x);
        float e_ = 0.f;
        #pragma unroll
        for (int i = 0; i < 8; ++i) e_ += vv[i] * ftanh(x[i] + qv[i]);
        #pragma unroll
        for (int m = 1; m < 64; m <<= 1) e_ += __shfl_xor(e_, m, 64);
        float wt = __expf(e_);          // |e| <= sum|v_att| ~ 8.2
        lsum += wt;
        float h[8]; unpack8(v.z, v.w, h);
        #pragma unroll
        for (int i = 0; i < 8; ++i) acc8[i] = fmaf(wt, h[i], acc8[i]);
      }
      *(f32x4*)&L.p1.red[w][l * 8]     = *(f32x4*)&acc8[0];
      *(f32x4*)&L.p1.red[w][l * 8 + 4] = *(f32x4*)&acc8[4];
      if (l == 0) L.p1.ls[w] = lsum;
      __syncthreads();
      float vsum = 0.f;
      #pragma unroll
      for (int ww = 0; ww < 8; ++ww) vsum += L.p1.red[ww][tid];
      atomicAdd(&g_.att_acc[((size_t)p * cB + b_att) * cE + tid], vsum);
      if (tid == 0){
        float ls = 0.f;
        #pragma unroll
        for (int i = 0; i < 8; ++i) ls += L.p1.ls[i];
        atomicAdd(&g_.att_l[p * cB + b_att], ls);
      }
    }
    __syncthreads();                     // drains adds (compiler waitcnt)
    if (tid == 0) sig(&ctl[AFLAG + blk], (u32)(s + 1));
    // ================= B =================================================
    if (blk < 128){
      if (tid < 64){
        pollge(ctl + AFLAG, 256, (u32)(s + 1));      // all att adds done
        pollge(ctl + G0FLAG, 64, (u32)s);            // g0(s) ready
      }
      __syncthreads();
      stage_att(L, g_.att_acc + (size_t)p * cB * cE, g_.att_l + p * cB, tid);
      __syncthreads();
      if (tid == 0) sig(&ctl[SFLAG + p * 128 + blk], (u32)(s >> 1) + 1u);
      // prefetch g0 gate-values + c0 (latency hides under gemv)
      float gpre[4], cpre = 0.f;
      int bb = tid >> 3, dc = tid & 7, d = blk * 8 + dc;
      if (tid < 256){
        #pragma unroll
        for (int g = 0; g < 4; ++g)
          gpre[g] = ld_sc(&g_.g0buf[(size_t)p * cB * 4096 + bb * 4096 + g * 1024 + d]);
        cpre = g_.c0[(size_t)p * cB * cD + bb * cD + d];
      }
      gemv_reg<4, 4, SPA>(wB, L, tid);
      __syncthreads();
      if (tid < 256){
        int mt = bb >> 4, rr = bb & 15;
        float gate[4];
        #pragma unroll
        for (int g = 0; g < 4; ++g){
          int jj = g * 8 + dc;
          float v = 0.f;
          #pragma unroll
          for (int kh = 0; kh < 4; ++kh)
            v += L.gv.acc[(jj >> 4) * 4 + kh][mt][rr][jj & 15];
          gate[g] = v * DS + gpre[g];
        }
        float c = fsigm(gate[1]) * cpre + fsigm(gate[0]) * ftanh(gate[2]);
        float z = fsigm(gate[3]) * ftanh(c);
        g_.c0[(size_t)(p ^ 1) * cB * cD + bb * cD + d] = c;   // block-private
        st_scb(&g_.z0f8[bb * cD + d], f2fp8(z * 8.f));
      }
      __syncthreads();
      if (tid == 0) sig(&ctl[Z0FLAG + blk], (u32)(s + 1));
    } else {
      if (tid < 64) pollge(ctl + Z1FLAG, 128, (u32)s);   // z1(s-1) ready
      __syncthreads();
      stage_z(L, g_.z1f8, tid);
      __syncthreads();
      gemv_reg<4, 8, SPZ>(wB, L, tid);
      __syncthreads();
      {
        const int jb = (blk - 128) * 32;
        int bb = tid >> 4, j2 = (tid & 15) * 2;
        int mt = bb >> 4, rr = bb & 15;
        #pragma unroll
        for (int k = 0; k < 2; ++k){
          int jj = j2 + k;
          float v = 0.f;
          #pragma unroll
          for (int kh = 0; kh < 4; ++kh)
            v += L.gv.acc[(jj >> 4) * 4 + kh][mt][rr][jj & 15];
          st_sc(&g_.hh1buf[bb * 4096 + jb + jj], v * DS + g_.bias01[jb + jj]);
        }
      }
      __syncthreads();
      if (tid == 0) sig(&ctl[HH1FLAG + (blk - 128)], (u32)(s + 1));
    }
    // ================= C =================================================
    if (blk < 128){
      if (tid < 64){
        pollge(ctl + Z0FLAG, 128, (u32)(s + 1));
        pollge(ctl + HH1FLAG, 128, (u32)(s + 1));
      }
      __syncthreads();
      stage_z(L, g_.z0f8, tid);
      __syncthreads();
      // prefetch hh1 gate-values + c1 (latency hides under gemv)
      float hpre[4], cpre = 0.f;
      int bb = tid >> 3, dc = tid & 7, d = blk * 8 + dc;
      if (tid < 256){
        #pragma unroll
        for (int g = 0; g < 4; ++g)
          hpre[g] = ld_sc(&g_.hh1buf[bb * 4096 + g * 1024 + d]);
        cpre = g_.c1[(size_t)p * cB * cD + bb * cD + d];
      }
      gemv_reg<4, 8, SPZ>(wC, L, tid);
      __syncthreads();
      if (tid < 256){
        int mt = bb >> 4, rr = bb & 15;
        float gate[4];
        #pragma unroll
        for (int g = 0; g < 4; ++g){
          int jj = g * 8 + dc;
          float v = 0.f;
          #pragma unroll
          for (int kh = 0; kh < 4; ++kh)
            v += L.gv.acc[(jj >> 4) * 4 + kh][mt][rr][jj & 15];
          gate[g] = v * DS + hpre[g];
        }
        float c = fsigm(gate[1]) * cpre + fsigm(gate[0]) * ftanh(gate[2]);
        float z = fsigm(gate[3]) * ftanh(c);
        g_.c1[(size_t)(p ^ 1) * cB * cD + bb * cD + d] = c;   // block-private
        g_.z1all[((size_t)s + 1) * cB * cD + bb * cD + d] = f2bf(z);
        st_scb(&g_.z1f8[bb * cD + d], f2fp8(z * 8.f));
      }
      __syncthreads();
      if (tid == 0) sig(&ctl[Z1FLAG + blk], (u32)(s + 1));
    } else if (blk < 192){
      if (tid < 64) pollge(ctl + Z0FLAG, 128, (u32)(s + 1));
      __syncthreads();
      stage_z(L, g_.z0f8, tid);
      __syncthreads();
      gemv_reg<2, 16, SPZ>(wC, L, tid);
      __syncthreads();
      if (s < cNS - 1){
        const int jb = (blk - 128) * 64;
        int bb = tid >> 4, j4 = (tid & 15) * 4;
        int mt = bb >> 4, rr = bb & 15;
        const u16* eyr = g_.eyproj + (((size_t)(s + 1) * cB + bb) * 4096) + jb + j4;
        #pragma unroll
        for (int k = 0; k < 4; ++k){
          int jj = j4 + k;
          float v = 0.f;
          #pragma unroll
          for (int kh = 0; kh < 2; ++kh)
            v += L.gv.acc[(jj >> 4) * 2 + kh][mt][rr][jj & 15];
          st_sc(&g_.g0buf[(size_t)(p ^ 1) * cB * 4096 + bb * 4096 + jb + jj],
                v * DS + bf2f(eyr[k]));
        }
      }
      __syncthreads();
      if (tid == 0) sig(&ctl[G0FLAG + (blk - 128)], (u32)(s + 1));
    } else if (blk < 208){
      if (tid < 64) pollge(ctl + Z0FLAG, 128, (u32)(s + 1));
      __syncthreads();
      stage_z(L, g_.z0f8, tid);
      __syncthreads();
      gemv_reg<4, 8, SPZ>(wC, L, tid);
      __syncthreads();
      if (s < cNS - 1){
        const int jb = (blk - 192) * 32;
        int bb = tid >> 4, j2 = (tid & 15) * 2;
        int mt = bb >> 4, rr = bb & 15;
        #pragma unroll
        for (int k = 0; k < 2; ++k){
          int jj = j2 + k;
          float v = 0.f;
          #pragma unroll
          for (int kh = 0; kh < 4; ++kh)
            v += L.gv.acc[(jj >> 4) * 4 + kh][mt][rr][jj & 15];
          st_sc(&g_.q[bb * cA + jb + jj], v * DS);
        }
      }
      __syncthreads();
      if (tid == 0) sig(&ctl[QFLAG + (blk - 192)], (u32)(s + 1));
    } else if (blk == 208){
      // re-zero parity buffer once all 128 B-blocks consumed it
      if (tid < 64) pollge(ctl + SFLAG + p * 128, 128, (u32)(s >> 1) + 1u);
      __syncthreads();
      {
        float* aa = g_.att_acc + (size_t)p * cB * cE;
        for (int i = tid; i < cB * cE; i += 512) st_sc(&aa[i], 0.f);
        if (tid < cB) st_sc(&g_.att_l[p * cB + tid], 0.f);
      }
      __syncthreads();
      if (tid == 0) sig(&ctl[ZDONEW + p * 16], (u32)(s >> 1) + 1u);
    }
  }
}

// ------------------------------ epilogue -----------------------------------
__global__ __launch_bounds__(256) void k_ce1(const u16* __restrict__ z1all,
    const u16* __restrict__ Woutb, const float* __restrict__ bout,
    const int* __restrict__ ys, float* __restrict__ pmax, float* __restrict__ psum,
    int* __restrict__ pai, float* __restrict__ tgtl){
  int blk = blockIdx.x;
  int sc = blk / 40, vc = blk % 40;
  int tid = threadIdx.x, w = tid >> 6, l = tid & 63;
  int kin = 8 * (l >> 4), col = l & 15;
  int v0 = vc * 128 + w * 32;
  int vA = v0 + col, vB = v0 + 16 + col;
  float boA = (vA < cV) ? bout[vA] : 0.f;
  float boB = (vB < cV) ? bout[vB] : 0.f;
  const u16* wrA = Woutb + (size_t)((vA < cV) ? vA : cV - 1) * cD;
  const u16* wrB = Woutb + (size_t)((vB < cV) ? vB : cV - 1) * cD;
  __shared__ int tgt_sh[32];
  __shared__ float rsm[4][32], rss[4][32];
  __shared__ int rsi[4][32];
  for (int si = 0; si < 5; ++si){
    int s = sc * 5 + si;
    if (tid < 32) tgt_sh[tid] = (s < cL) ? ys[tid * cL + s] : EOS;
    __syncthreads();
    const u16* z1s = z1all + ((size_t)s + 1) * cB * cD;
    f32x4 aA0 = {0.f,0.f,0.f,0.f}, aA1 = {0.f,0.f,0.f,0.f};
    f32x4 aB0 = {0.f,0.f,0.f,0.f}, aB1 = {0.f,0.f,0.f,0.f};
    for (int kc = 0; kc < 32; ++kc){
      int k = kc * 32 + kin;
      s16x8 x0 = LD8(z1s + (size_t)col * cD + k);
      s16x8 x1 = LD8(z1s + (size_t)(16 + col) * cD + k);
      s16x8 bA = LD8(wrA + k);
      s16x8 bB = LD8(wrB + k);
      aA0 = MFMA(x0, bA, aA0); aA1 = MFMA(x1, bA, aA1);
      aB0 = MFMA(x0, bB, aB0); aB1 = MFMA(x1, bB, aB1);
    }
    #pragma unroll
    for (int mt = 0; mt < 2; ++mt)
    #pragma unroll
    for (int reg = 0; reg < 4; ++reg){
      int row = mt * 16 + (l >> 4) * 4 + reg;
      float va = (mt ? aA1[reg] : aA0[reg]) + boA; if (vA >= cV) va = -1e30f;
      float vb = (mt ? aB1[reg] : aB0[reg]) + boB; if (vB >= cV) vb = -1e30f;
      int tg = tgt_sh[row];
      if (vA == tg) tgtl[(size_t)s * cB + row] = va;
      if (vB == tg) tgtl[(size_t)s * cB + row] = vb;
      float mx = fmaxf(va, vb);
      int ix = (va >= vb) ? vA : vB;
      #pragma unroll
      for (int m = 1; m < 16; m <<= 1){
        float om = __shfl_xor(mx, m, 64);
        int oi = __shfl_xor(ix, m, 64);
        if (om > mx || (om == mx && oi < ix)){ mx = om; ix = oi; }
      }
      float se = __expf(va - mx) + __expf(vb - mx);
      #pragma unroll
      for (int m = 1; m < 16; m <<= 1) se += __shfl_xor(se, m, 64);
      if ((l & 15) == 0){ rsm[w][row] = mx; rss[w][row] = se; rsi[w][row] = ix; }
    }
    __syncthreads();
    if (tid < 32){
      int b = tid;
      float gm = -1e30f;
      #pragma unroll
      for (int w2 = 0; w2 < 4; ++w2) gm = fmaxf(gm, rsm[w2][b]);
      float gs = 0.f; float bv = -1e30f; int bix = 0x7fffffff;
      #pragma unroll
      for (int w2 = 0; w2 < 4; ++w2){
        gs += rss[w2][b] * __expf(rsm[w2][b] - gm);
        float v = rsm[w2][b]; int ii = rsi[w2][b];
        if (v > bv || (v == bv && ii < bix)){ bv = v; bix = ii; }
      }
      size_t o = ((size_t)s * cB + b) * 40 + vc;
      pmax[o] = gm; psum[o] = gs; pai[o] = bix;
    }
    __syncthreads();
  }
}

__global__ __launch_bounds__(64) void k_ce2(const float* __restrict__ pmax,
    const float* __restrict__ psum, const int* __restrict__ pai,
    const float* __restrict__ tgtl, const int* __restrict__ ys,
    float* __restrict__ cestep){
  int s = blockIdx.x, tid = threadIdx.x;
  float nll = 0.f, cor = 0.f;
  if (tid < 32){
    int b = tid;
    size_t o = ((size_t)s * cB + b) * 40;
    float gm = -1e30f;
    for (int c = 0; c < 40; ++c) gm = fmaxf(gm, pmax[o + c]);
    float gs = 0.f; float bv = -1e30f; int bix = 0x7fffffff;
    for (int c = 0; c < 40; ++c){
      gs += psum[o + c] * __expf(pmax[o + c] - gm);
      float v = pmax[o + c]; int ii = pai[o + c];
      if (v > bv || (v == bv && ii < bix)){ bv = v; bix = ii; }
    }
    nll = __logf(gs) + gm - tgtl[(size_t)s * cB + b];
    int tgt = (s < cL) ? ys[b * cL + s] : EOS;
    cor = (bix == tgt) ? 1.f : 0.f;
  }
  #pragma unroll
  for (int m = 1; m < 64; m <<= 1){
    nll += __shfl_xor(nll, m, 64); cor += __shfl_xor(cor, m, 64);
  }
  if (tid == 0){ cestep[s * 2] = nll; cestep[s * 2 + 1] = cor; }
}

__global__ __launch_bounds__(256) void k_ce3(const float* __restrict__ cestep,
                                             float* __restrict__ out){
  int tid = threadIdx.x;
  float nll = 0.f, cor = 0.f;
  for (int s = tid; s < cNS; s += 256){ nll += cestep[s * 2]; cor += cestep[s * 2 + 1]; }
  __shared__ float sn[4], sc_[4];
  int w = tid >> 6, l = tid & 63;
  #pragma unroll
  for (int m = 1; m < 64; m <<= 1){
    nll += __shfl_xor(nll, m, 64); cor += __shfl_xor(cor, m, 64);
  }
  if (l == 0){ sn[w] = nll; sc_[w] = cor; }
  __syncthreads();
  if (tid == 0){
    float a = sn[0] + sn[1] + sn[2] + sn[3];
    float b = sc_[0] + sc_[1] + sc_[2] + sc_[3];
    out[0] = a / (float)(cB * cNS) * (float)cL;
    out[1] = b / (float)(cB * cNS);
  }
}

// ------------------------------- host --------------------------------------
extern "C" void kernel_launch(void* const* d_in, const int* in_sizes, int n_in,
                              void* d_out, int out_size, void* d_ws, size_t ws_size,
                              hipStream_t stream){
  const float* hpad = (const float*)d_in[0];
  const int*   hlen = (const int*)d_in[1];
  const int*   ys   = (const int*)d_in[2];
  const float* embed= (const float*)d_in[3];
  const float* Wout = (const float*)d_in[4];
  const float* bout = (const float*)d_in[5];
  const float* Wenc = (const float*)d_in[6];
  const float* Wdec = (const float*)d_in[7];
  const float* vatt = (const float*)d_in[8];
  const float* Wih0 = (const float*)d_in[9];
  const float* bih0 = (const float*)d_in[10];
  const float* Whh0 = (const float*)d_in[11];
  const float* bhh0 = (const float*)d_in[12];
  const float* Wih1 = (const float*)d_in[13];
  const float* bih1 = (const float*)d_in[14];
  const float* Whh1 = (const float*)d_in[15];
  const float* bhh1 = (const float*)d_in[16];
  (void)in_sizes; (void)n_in; (void)out_size; (void)ws_size;

  char* base = (char*)d_ws;
  size_t off = 0;
  auto alloc = [&](size_t bytes) -> void* {
    void* r = base + off; off += (bytes + 255) & ~(size_t)255; return r;
  };
  u32*   ctl     = (u32*)  alloc(1024 * 4);
  u16*   hpadM   = (u16*)  alloc((size_t)cB * cT * cE * 2);
  u8*    ph8     = (u8*)   alloc((size_t)cB * cT * 1024);
  u16*   embb    = (u16*)  alloc((size_t)cV * cD * 2);
  u16*   ey      = (u16*)  alloc((size_t)cNS * cB * cD * 2);
  u16*   eyproj  = (u16*)  alloc((size_t)cNS * cB * 4096 * 2);
  u16*   z1all   = (u16*)  alloc((size_t)(cNS + 1) * cB * cD * 2);
  u16*   WencT   = (u16*)  alloc((size_t)cA * cE * 2);
  u16*   Wih0m   = (u16*)  alloc((size_t)4096 * cD * 2);
  u16*   Woutb   = (u16*)  alloc((size_t)cV * cD * 2);
  u8*    Wapf8   = (u8*)   alloc((size_t)4096 * 512);
  u8*    Wih1f8  = (u8*)   alloc((size_t)4096 * 1024);
  u8*    Whh1f8  = (u8*)   alloc((size_t)4096 * 1024);
  u8*    Whh0f8  = (u8*)   alloc((size_t)4096 * 1024);
  u8*    WdecTf8 = (u8*)   alloc((size_t)512 * 1024);
  float* bias01  = (float*)alloc(4096 * 4);
  float* qbuf    = (float*)alloc((size_t)cB * cA * 4);
  float* att_acc = (float*)alloc((size_t)2 * cB * cE * 4);
  float* att_l   = (float*)alloc((size_t)2 * cB * 4);
  float* g0buf   = (float*)alloc((size_t)2 * cB * 4096 * 4);
  float* hh1buf  = (float*)alloc((size_t)cB * 4096 * 4);
  u8*    z0f8    = (u8*)   alloc((size_t)cB * cD);
  u8*    z1f8    = (u8*)   alloc((size_t)cB * cD);
  float* c0      = (float*)alloc((size_t)2 * cB * cD * 4);
  float* c1      = (float*)alloc((size_t)2 * cB * cD * 4);
  float* pmax    = (float*)alloc((size_t)cNS * cB * 40 * 4);
  float* psum    = (float*)alloc((size_t)cNS * cB * 40 * 4);
  int*   pai     = (int*)  alloc((size_t)cNS * cB * 40 * 4);
  float* tgtl    = (float*)alloc((size_t)cNS * cB * 4);
  float* cestep  = (float*)alloc((size_t)cNS * 2 * 4);

  k_init<<<64, 256, 0, stream>>>(ctl, qbuf, c0, c1, z1f8, att_acc, att_l);
  k_cvt<<<2048, 256, 0, stream>>>(hpad, hpadM, cB * cT * cE / 4);
  k_cvt8I<<<1024, 256, 0, stream>>>(hpad, ph8, cB * cT * 64);
  k_cvt<<<2048, 256, 0, stream>>>(embed, embb, cV * cD / 4);
  k_cvt<<<2048, 256, 0, stream>>>(Wout, Woutb, cV * cD / 4);
  k_slice<<<1024, 256, 0, stream>>>(Wih0, Wih0m, 4096 * cD, 10, 1536, 0);
  k_transp<<<256, 256, 0, stream>>>(Wenc, WencT, cA * cE, 9, cA);
  k_bias<<<16, 256, 0, stream>>>(bih1, bhh1, bias01, 4096);
  k_wf8perm<<<512, 256, 0, stream>>>(Wih0, Wapf8, 4096 * 512 / 4, 9, 1536, 1024);
  k_wf8perm<<<1024, 256, 0, stream>>>(Wih1, Wih1f8, 4096 * 1024 / 4, 10, 1024, 0);
  k_wf8<<<1024, 256, 0, stream>>>(Whh1, Whh1f8, 4096 * 1024 / 4);
  k_wf8<<<1024, 256, 0, stream>>>(Whh0, Whh0f8, 4096 * 1024 / 4);
  k_wf8t<<<128, 256, 0, stream>>>(Wdec, WdecTf8, 512 * 1024 / 4);
  k_gather<<<1200, 256, 0, stream>>>(embb, ys, ey, cNS * cB * 128);
  k_pe2<<<200, 512, 0, stream>>>(hpadM, WencT, ph8);
  k_ey2<<<dim3(38, 8), 512, 0, stream>>>(ey, Wih0m, bih0, bhh0, eyproj, g0buf);

  LoopArgs la;
  la.hlen = hlen; la.ph8 = ph8; la.eyproj = eyproj;
  la.Wapf8 = Wapf8; la.Whh1f8 = Whh1f8; la.Wih1f8 = Wih1f8;
  la.Whh0f8 = Whh0f8; la.WdecTf8 = WdecTf8;
  la.vatt = vatt; la.bias01 = bias01;
  la.q = qbuf; la.att_acc = att_acc; la.att_l = att_l;
  la.g0buf = g0buf; la.hh1buf = hh1buf; la.z0f8 = z0f8; la.z1f8 = z1f8;
  la.c0 = c0; la.c1 = c1; la.z1all = z1all; la.ctl = ctl;
  k_loop<<<NBLK, 512, 0, stream>>>(la);

  k_ce1<<<1200, 256, 0, stream>>>(z1all, Woutb, bout, ys, pmax, psum, pai, tgtl);
  k_ce2<<<cNS, 64, 0, stream>>>(pmax, psum, pai, tgtl, ys, cestep);
  k_ce3<<<1, 256, 0, stream>>>(cestep, (float*)d_out);
}

// Round 9
// 4027.780 us; speedup vs baseline: 2.0014x; 1.2047x over previous
//
#include <hip/hip_runtime.h>

// ---------------------------------------------------------------------------
// Decoder_60868276519063: attention-LSTM decoder forward (loss, acc)
// B=32 T=800 E=512 D=1024 V=5000 L=149 (150 steps) A=512
// Round 9: r8 skeleton + (1) pk-bf16 atomics for attention combine,
// (2) step-tagged bf16 payloads for q/hh1/g0 (no QFLAG/HH1FLAG/G0FLAG,
// optimistic prefetch + post-GEMV verify), (3) LDS q broadcast,
// (4) merged A-gate. Store-flags remain only for AFLAG/Z0/Z1/SFLAG/ZDONE.
// ---------------------------------------------------------------------------

typedef unsigned short u16;
typedef unsigned char u8;
typedef unsigned int u32;
typedef long long i64;
typedef unsigned long long u64;
typedef float f32x4 __attribute__((ext_vector_type(4)));
typedef float f32x2 __attribute__((ext_vector_type(2)));
typedef short s16x8 __attribute__((ext_vector_type(8)));

constexpr int cB = 32, cT = 800, cE = 512, cD = 1024, cV = 5000, cL = 149,
              cNS = 150, cA = 512;
constexpr int SOS = 1, EOS = 2;
constexpr int NBLK = 256;
constexpr float DS = 1.0f / 128.0f;   // fp8 descale: W x16, x x8

// flag indices into ctl[] (u32 units); store-based, one word per producer
constexpr int AFLAG = 0;     // 256
constexpr int Z0FLAG = 256;  // 128
constexpr int Z1FLAG = 384;  // 128
constexpr int SFLAG = 512;   // +p*128, 128
constexpr int ZDONE = 768;   // +p*16

__device__ __forceinline__ float bf2f(u16 x){
  union { u32 u; float f; } v; v.u = ((u32)x) << 16; return v.f;
}
__device__ __forceinline__ u16 f2bf(float f){
  union { float f; u32 u; } v; v.f = f;
  u32 r = v.u + 0x7FFFu + ((v.u >> 16) & 1u);
  return (u16)(r >> 16);
}
__device__ __forceinline__ float frcp(float x){ return __builtin_amdgcn_rcpf(x); }
__device__ __forceinline__ float fsigm(float x){ return frcp(1.f + __expf(-x)); }
__device__ __forceinline__ float ftanh(float x){
  float u = __expf(2.f * x);
  return 1.f - 2.f * frcp(u + 1.f);
}
__device__ __forceinline__ f32x4 MFMA(s16x8 a, s16x8 b, f32x4 c){
  return __builtin_amdgcn_mfma_f32_16x16x32_bf16(a, b, c, 0, 0, 0);
}
__device__ __forceinline__ f32x4 MFMA8(i64 a, i64 b, f32x4 c){
  return __builtin_amdgcn_mfma_f32_16x16x32_fp8_fp8(a, b, c, 0, 0, 0);
}
__device__ __forceinline__ s16x8 LD8(const u16* p){ return *(const s16x8*)p; }
__device__ __forceinline__ u8 f2fp8(float x){
  return (u8)(__builtin_amdgcn_cvt_pk_fp8_f32(x, x, 0, false) & 0xFF);
}
__device__ __forceinline__ u32 pk4(float a, float b, float c, float d){
  u32 w = (u32)__builtin_amdgcn_cvt_pk_fp8_f32(a, b, 0, false);
  w = (u32)__builtin_amdgcn_cvt_pk_fp8_f32(c, d, (int)w, true);
  return w;
}
__device__ __forceinline__ void unpack8(u32 lo, u32 hi, float* o){
  f32x2 a = __builtin_amdgcn_cvt_pk_f32_fp8((int)lo, false);
  f32x2 b = __builtin_amdgcn_cvt_pk_f32_fp8((int)lo, true);
  f32x2 c = __builtin_amdgcn_cvt_pk_f32_fp8((int)hi, false);
  f32x2 d = __builtin_amdgcn_cvt_pk_f32_fp8((int)hi, true);
  o[0]=a[0]; o[1]=a[1]; o[2]=b[0]; o[3]=b[1];
  o[4]=c[0]; o[5]=c[1]; o[6]=d[0]; o[7]=d[1];
}

// ---- agent-scope (sc1) relaxed accessors (coherent at L3, no fences) ------
__device__ __forceinline__ float ld_sc(const float* p){
  return __hip_atomic_load(p, __ATOMIC_RELAXED, __HIP_MEMORY_SCOPE_AGENT);
}
__device__ __forceinline__ void st_sc(float* p, float v){
  __hip_atomic_store(p, v, __ATOMIC_RELAXED, __HIP_MEMORY_SCOPE_AGENT);
}
__device__ __forceinline__ u64 ld_sc8(const void* p){
  return __hip_atomic_load((const u64*)p, __ATOMIC_RELAXED, __HIP_MEMORY_SCOPE_AGENT);
}
__device__ __forceinline__ void st_sc8(void* p, u64 v){
  __hip_atomic_store((u64*)p, v, __ATOMIC_RELAXED, __HIP_MEMORY_SCOPE_AGENT);
}
__device__ __forceinline__ u32 ld_su(const u32* p){
  return __hip_atomic_load(p, __ATOMIC_RELAXED, __HIP_MEMORY_SCOPE_AGENT);
}
__device__ __forceinline__ void st_su(u32* p, u32 v){
  __hip_atomic_store(p, v, __ATOMIC_RELAXED, __HIP_MEMORY_SCOPE_AGENT);
}
__device__ __forceinline__ void st_scb(u8* p, u8 v){
  __hip_atomic_store(p, v, __ATOMIC_RELAXED, __HIP_MEMORY_SCOPE_AGENT);
}
__device__ __forceinline__ void atomic_pk_bf16(u32* dst, u32 data){
  asm volatile("global_atomic_pk_add_bf16 %0, %1, off"
               :: "v"(dst), "v"(data) : "memory");
}

// poll n flag words (store-based, monotone) until all >= target (wave 0)
__device__ __forceinline__ void pollge(const u32* f, int n, u32 target){
  const int lane = threadIdx.x & 63;
  for(;;){
    bool ok = true;
    for (int i = lane; i < n; i += 64) ok &= (ld_su(f + i) >= target);
    if (__all(ok)) break;
    __builtin_amdgcn_s_sleep(1);
  }
}
__device__ __forceinline__ void sig(u32* f, u32 v){
  asm volatile("s_waitcnt vmcnt(0)" ::: "memory");
  st_su(f, v);
}

// ------------------------------- prologue ----------------------------------
__global__ void k_init(u32* ctl, u32* qt, float* c0, float* c1, u8* z1f8,
                       u32* att_pk, float* att_l, u32* hh1t){
  int i = blockIdx.x * blockDim.x + threadIdx.x, n = gridDim.x * blockDim.x;
  for (int k = i; k < 1024; k += n) ctl[k] = 0;
  for (int k = i; k < cB * cA; k += n) qt[k] = 0;            // tag0|bf16(0)
  for (int k = i; k < 2 * cB * cD; k += n){ c0[k] = 0.f; c1[k] = 0.f; }
  for (int k = i; k < cB * cD / 4; k += n) ((u32*)z1f8)[k] = 0;
  for (int k = i; k < 2 * cB * 256; k += n) att_pk[k] = 0;
  for (int k = i; k < 2 * cB; k += n) att_l[k] = 0.f;
  for (int k = i; k < cB * 4096; k += n) hh1t[k] = 0xFFFF0000u; // invalid tag
}

__global__ void k_cvt(const float* __restrict__ s, u16* __restrict__ d, int n4){
  int i = blockIdx.x * blockDim.x + threadIdx.x, st = gridDim.x * blockDim.x;
  for (int k = i; k < n4; k += st){
    float4 v = ((const float4*)s)[k];
    ushort4 o; o.x = f2bf(v.x); o.y = f2bf(v.y); o.z = f2bf(v.z); o.w = f2bf(v.w);
    ((ushort4*)d)[k] = o;
  }
}

// hpad -> fp8 h-half of interleaved ph8 rows: [grp*16+8 .. +15]
__global__ void k_cvt8I(const float* __restrict__ s, u8* __restrict__ d, int n){
  int i = blockIdx.x * blockDim.x + threadIdx.x, st = gridDim.x * blockDim.x;
  for (int k = i; k < n; k += st){
    int row = k >> 6, grp = k & 63;
    const float4* p = (const float4*)(s + (size_t)row * 512 + grp * 8);
    float4 v0 = p[0], v1 = p[1];
    u32 lo = pk4(v0.x, v0.y, v0.z, v0.w);
    u32 hi = pk4(v1.x, v1.y, v1.z, v1.w);
    *(uint2*)(d + (size_t)row * 1024 + grp * 16 + 8) = make_uint2(lo, hi);
  }
}

__global__ void k_slice(const float* __restrict__ s, u16* __restrict__ d, int n,
                        int cshift, int srcld, int coff){
  int i = blockIdx.x * blockDim.x + threadIdx.x, st = gridDim.x * blockDim.x;
  int cmask = (1 << cshift) - 1;
  for (int k = i; k < n; k += st){
    int r = k >> cshift, c = k & cmask;
    d[k] = f2bf(s[(size_t)r * srcld + coff + c]);
  }
}

__global__ void k_transp(const float* __restrict__ s, u16* __restrict__ d, int n,
                         int rshift, int csrc){
  int i = blockIdx.x * blockDim.x + threadIdx.x, st = gridDim.x * blockDim.x;
  int mask = (1 << rshift) - 1;
  for (int k = i; k < n; k += st){
    int dd = k & mask, a = k >> rshift;
    d[k] = f2bf(s[(size_t)dd * csrc + a]);
  }
}

__global__ void k_bias(const float* a, const float* b, float* o, int n){
  int i = blockIdx.x * blockDim.x + threadIdx.x, st = gridDim.x * blockDim.x;
  for (int k = i; k < n; k += st) o[k] = a[k] + b[k];
}

// fp8 weight convert, x16 scale, row-permuted: dst row R=j*32+jj, jj=g*8+c
__global__ void k_wf8perm(const float* __restrict__ s, u8* __restrict__ d,
                          int n4, int kshift, int srcld, int coff){
  int i = blockIdx.x * blockDim.x + threadIdx.x, st = gridDim.x * blockDim.x;
  int kmask = (1 << kshift) - 1;
  for (int k = i; k < n4; k += st){
    int flat = k * 4;
    int R = flat >> kshift, kk = flat & kmask;
    int j = R >> 5, jj = R & 31, g = jj >> 3, c = jj & 7;
    const float* p = s + (size_t)(g * 1024 + j * 8 + c) * srcld + coff + kk;
    ((u32*)d)[k] = pk4(p[0]*16.f, p[1]*16.f, p[2]*16.f, p[3]*16.f);
  }
}

__global__ void k_wf8(const float* __restrict__ s, u8* __restrict__ d, int n4){
  int i = blockIdx.x * blockDim.x + threadIdx.x, st = gridDim.x * blockDim.x;
  for (int k = i; k < n4; k += st){
    float4 v = ((const float4*)s)[k];
    ((u32*)d)[k] = pk4(v.x*16.f, v.y*16.f, v.z*16.f, v.w*16.f);
  }
}

// WdecT fp8: dst[a][dd] = Wdec[dd][a] * 16, dst [512][1024]
__global__ void k_wf8t(const float* __restrict__ s, u8* __restrict__ d, int n4){
  int i = blockIdx.x * blockDim.x + threadIdx.x, st = gridDim.x * blockDim.x;
  for (int k = i; k < n4; k += st){
    int flat = k * 4;
    int a = flat >> 10, dd = flat & 1023;
    ((u32*)d)[k] = pk4(s[(size_t)(dd+0)*512 + a]*16.f,
                       s[(size_t)(dd+1)*512 + a]*16.f,
                       s[(size_t)(dd+2)*512 + a]*16.f,
                       s[(size_t)(dd+3)*512 + a]*16.f);
  }
}

// ey[r][:] = embb[tok(r)][:]  (bf16 gather), r = s*32+b
__global__ void k_gather(const u16* __restrict__ embb, const int* __restrict__ ys,
                         u16* __restrict__ ey, int n16){
  int i = blockIdx.x * blockDim.x + threadIdx.x, st = gridDim.x * blockDim.x;
  for (int k = i; k < n16; k += st){
    int r = k >> 7, seg = k & 127;
    int s = r >> 5, b = r & 31;
    int tok = (s == 0) ? SOS : ys[b * cL + (s - 1)];
    ((uint4*)ey)[(size_t)r * 128 + seg] =
        ((const uint4*)embb)[(size_t)tok * 128 + seg];
  }
}

// pe GEMM: [25600x512] @ WencT[512 a][512 e]^T -> fp8 into ph8 pe-half
__global__ __launch_bounds__(512, 1) void k_pe2(const u16* __restrict__ A,
    const u16* __restrict__ Bw, u8* __restrict__ ph8){
  int tid = threadIdx.x, w = tid >> 6, l = tid & 63;
  int col = l & 15, kin = 8 * (l >> 4);
  int mw = w >> 2, nw = w & 3;
  int m0 = blockIdx.x * 128 + mw * 64;
  int n0 = nw * 128;
  f32x4 acc[4][8] = {};
  for (int kc = 0; kc < 16; ++kc){
    int k = kc * 32 + kin;
    s16x8 af[4], bf[8];
    #pragma unroll
    for (int i = 0; i < 4; ++i) af[i] = LD8(A + (size_t)(m0 + i*16 + col)*512 + k);
    #pragma unroll
    for (int j = 0; j < 8; ++j) bf[j] = LD8(Bw + (size_t)(n0 + j*16 + col)*512 + k);
    #pragma unroll
    for (int i = 0; i < 4; ++i)
      #pragma unroll
      for (int j = 0; j < 8; ++j) acc[i][j] = MFMA(af[i], bf[j], acc[i][j]);
  }
  int hi4 = (l >> 4) * 4;
  #pragma unroll
  for (int i = 0; i < 4; ++i)
    #pragma unroll
    for (int j = 0; j < 8; ++j){
      int a0 = n0 + j * 16 + col;
      size_t boff = ((size_t)(a0 >> 3) << 4) + (a0 & 7);
      #pragma unroll
      for (int r = 0; r < 4; ++r){
        int row = m0 + i * 16 + hi4 + r;
        ph8[(size_t)row * 1024 + boff] = f2fp8(acc[i][j][r]);
      }
    }
}

// eyproj GEMM: ey[4800x1024] @ Wih0m[4096x1024]^T + biases -> bf16 eyproj
// + tagged u32 (tag0) g0t for step 0
__global__ __launch_bounds__(512, 1) void k_ey2(const u16* __restrict__ ey,
    const u16* __restrict__ Wm, const float* __restrict__ bih0,
    const float* __restrict__ bhh0, u16* __restrict__ eyproj,
    u32* __restrict__ g0t){
  int tid = threadIdx.x, w = tid >> 6, l = tid & 63;
  int col = l & 15, kin = 8 * (l >> 4);
  int mw = w >> 2, nw = w & 3;
  int m0 = blockIdx.x * 128 + mw * 64;
  int n0 = blockIdx.y * 512 + nw * 128;
  f32x4 acc[4][8] = {};
  for (int kc = 0; kc < 32; ++kc){
    int k = kc * 32 + kin;
    s16x8 af[4], bf[8];
    #pragma unroll
    for (int i = 0; i < 4; ++i){
      int ar = m0 + i * 16 + col; ar = (ar < 4800) ? ar : 0;
      af[i] = LD8(ey + (size_t)ar * 1024 + k);
    }
    #pragma unroll
    for (int j = 0; j < 8; ++j) bf[j] = LD8(Wm + (size_t)(n0 + j*16 + col)*1024 + k);
    #pragma unroll
    for (int i = 0; i < 4; ++i)
      #pragma unroll
      for (int j = 0; j < 8; ++j) acc[i][j] = MFMA(af[i], bf[j], acc[i][j]);
  }
  int hi4 = (l >> 4) * 4;
  #pragma unroll
  for (int i = 0; i < 4; ++i)
    #pragma unroll
    for (int j = 0; j < 8; ++j){
      int jc = n0 + j * 16 + col;
      float bj = bih0[jc] + bhh0[jc];
      #pragma unroll
      for (int r = 0; r < 4; ++r){
        int row = m0 + i * 16 + hi4 + r;
        if (row < 4800){
          float val = acc[i][j][r] + bj;
          eyproj[(size_t)row * 4096 + jc] = f2bf(val);
          if (row < 32) g0t[(size_t)row * 4096 + jc] = (u32)f2bf(val); // tag0
        }
      }
    }
}

// ------------------------------ main loop ----------------------------------
struct LoopArgs {
  const int* hlen;
  const u8* ph8;
  const u16* eyproj;
  const u8* Wapf8; const u8* Whh1f8; const u8* Wih1f8; const u8* Whh0f8;
  const u8* WdecTf8;
  const float* vatt; const float* bias01;
  u32* qt; u32* att_pk; float* att_l;
  u32* g0t; u32* hh1t; u8* z0f8; u8* z1f8;
  float* c0; float* c1; u16* z1all;
  u32* ctl;
};

// LDS x row strides (bytes)
constexpr int SPZ = 1048;   // K=1024 rows
constexpr int SPA = 536;    // K=512 rows

struct P1Lds { float red[8][512]; float ls[8]; float qsh[512]; };
struct GvLds { u8 x[32 * SPZ]; float acc[8][2][16][17]; };
union LoopLds { P1Lds p1; GvLds gv; };

// stage att (pk-bf16 src, normalize by att_l, x8) -> fp8 LDS x[32][512]
__device__ __forceinline__ void stage_att(LoopLds& L, const u32* att_pk,
                                          const float* att_l, int tid){
  int r = tid >> 4, cp = (tid & 15) * 16;   // 16 pairs = 32 e
  float sc = 8.0f * frcp(ld_sc(att_l + r));
  const u32* src = att_pk + (size_t)r * 256 + cp;
  u64 v[8];
  #pragma unroll
  for (int i = 0; i < 8; ++i) v[i] = ld_sc8(src + i * 2);
  u32 wd[8];
  #pragma unroll
  for (int i = 0; i < 8; ++i){
    u32 a = (u32)v[i], b = (u32)(v[i] >> 32);
    wd[i] = pk4(bf2f((u16)a) * sc, bf2f((u16)(a >> 16)) * sc,
                bf2f((u16)b) * sc, bf2f((u16)(b >> 16)) * sc);
  }
  uint2* dst = (uint2*)&L.gv.x[r * SPA + (tid & 15) * 32];
  dst[0] = make_uint2(wd[0], wd[1]);
  dst[1] = make_uint2(wd[2], wd[3]);
  dst[2] = make_uint2(wd[4], wd[5]);
  dst[3] = make_uint2(wd[6], wd[7]);
}

// stage fp8 z[32][1024] (sc1) -> LDS x, SP=SPZ
__device__ __forceinline__ void stage_z(LoopLds& L, const u8* zf8, int tid){
  int r = tid >> 4, c0 = (tid & 15) * 64;
  const u8* src = zf8 + (size_t)r * 1024 + c0;
  u64 v[8];
  #pragma unroll
  for (int i = 0; i < 8; ++i) v[i] = ld_sc8(src + i * 8);
  u64* dst = (u64*)&L.gv.x[r * SPZ + c0];
  #pragma unroll
  for (int i = 0; i < 8; ++i) dst[i] = v[i];
}

// block GEMV from register-resident weights: wave w: nt = w/KH, kh = w%KH.
template<int KH, int ITERS, int SP>
__device__ __forceinline__ void gemv_reg(const i64* wreg, LoopLds& L, int tid){
  const int w = tid >> 6, l = tid & 63;
  const int col = l & 15, kin = 8 * (l >> 4);
  const int kh = (KH == 4) ? (w & 3) : (w & 1);
  constexpr int KB = ITERS * 32;
  const u8* xr = &L.gv.x[col * SP + kh * KB + kin];
  f32x4 a0 = {0.f,0.f,0.f,0.f}, a1 = {0.f,0.f,0.f,0.f};
  #pragma unroll
  for (int kc = 0; kc < ITERS; ++kc){
    i64 x0 = *(const i64*)(xr + kc * 32);
    i64 x1 = *(const i64*)(xr + 16 * SP + kc * 32);
    a0 = MFMA8(x0, wreg[kc], a0);
    a1 = MFMA8(x1, wreg[kc], a1);
  }
  const int hi4 = (l >> 4) * 4;
  #pragma unroll
  for (int r = 0; r < 4; ++r){
    L.gv.acc[w][0][hi4 + r][col] = a0[r];
    L.gv.acc[w][1][hi4 + r][col] = a1[r];
  }
}

__global__ __launch_bounds__(512, 1) void k_loop(LoopArgs g_){
  __shared__ __align__(16) LoopLds L;
  __shared__ __align__(16) u8 ph8_lds[100 * 1024];
  const int blk = blockIdx.x, tid = threadIdx.x;
  const int w = tid >> 6, l = tid & 63;
  const int col = l & 15, kin = 8 * (l >> 4);
  const int b_att = blk >> 3, oct = blk & 7;
  const int hl = g_.hlen[b_att];
  const int t0 = oct * 100;
  const int t1 = (t0 + 100 < hl) ? t0 + 100 : hl;
  const int nrow = t1 - t0;
  u32* ctl = g_.ctl;
  float vv[8];
  #pragma unroll
  for (int i = 0; i < 8; ++i) vv[i] = g_.vatt[l * 8 + i];
  for (int idx = tid; idx < nrow * 64; idx += 512){
    int rr = idx >> 6, gg = idx & 63;
    *(uint4*)&ph8_lds[rr * 1024 + gg * 16] =
        *(const uint4*)(g_.ph8 + ((size_t)b_att * cT + t0 + rr) * 1024 + gg * 16);
  }
  // ---- preload step-invariant weight fragments into registers ----
  i64 wB[8], wC[16];
  {
    const int nt4 = w >> 2, kh4 = w & 3;
    const int nt2 = w >> 1, kh2 = w & 1;
    if (blk < 128){
      const u8* wr = g_.Wapf8 + (size_t)blk * 32 * 512 +
                     (size_t)(nt4 * 16 + col) * 512 + kh4 * 128 + kin;
      #pragma unroll
      for (int kc = 0; kc < 4; ++kc) wB[kc] = *(const i64*)(wr + kc * 32);
      const u8* wr2 = g_.Wih1f8 + (size_t)blk * 32 * 1024 +
                      (size_t)(nt4 * 16 + col) * 1024 + kh4 * 256 + kin;
      #pragma unroll
      for (int kc = 0; kc < 8; ++kc) wC[kc] = *(const i64*)(wr2 + kc * 32);
    } else {
      const u8* wr = g_.Whh1f8 + (size_t)(blk - 128) * 32 * 1024 +
                     (size_t)(nt4 * 16 + col) * 1024 + kh4 * 256 + kin;
      #pragma unroll
      for (int kc = 0; kc < 8; ++kc) wB[kc] = *(const i64*)(wr + kc * 32);
      if (blk < 192){
        const u8* wr2 = g_.Whh0f8 + (size_t)(blk - 128) * 64 * 1024 +
                        (size_t)(nt2 * 16 + col) * 1024 + kh2 * 512 + kin;
        #pragma unroll
        for (int kc = 0; kc < 16; ++kc) wC[kc] = *(const i64*)(wr2 + kc * 32);
      } else if (blk < 208){
        const u8* wr2 = g_.WdecTf8 + (size_t)(blk - 192) * 32 * 1024 +
                        (size_t)(nt4 * 16 + col) * 1024 + kh4 * 256 + kin;
        #pragma unroll
        for (int kc = 0; kc < 8; ++kc) wC[kc] = *(const i64*)(wr2 + kc * 32);
      }
    }
  }
  __syncthreads();

  for (int s = 0; s < cNS; ++s){
    const int p = s & 1;
    // ================= A: attention (tagged-q gate) ======================
    if (nrow > 0){
      if (w == 0){
        const u32* qrow = g_.qt + b_att * cA + l * 8;
        const u64 tmask = 0xFFFF0000FFFF0000ULL;
        const u64 texp = ((u64)(u32)s << 48) | ((u64)(u32)s << 16);
        u64 qw[4];
        for(;;){
          bool ok = true;
          #pragma unroll
          for (int i = 0; i < 4; ++i){
            qw[i] = ld_sc8(qrow + i * 2);
            ok &= ((qw[i] & tmask) == texp);
          }
          if (l == 0)
            ok &= (ld_su(&ctl[ZDONE + p * 16]) >= (u32)(s >> 1));
          if (__all(ok)) break;
          __builtin_amdgcn_s_sleep(1);
        }
        #pragma unroll
        for (int i = 0; i < 4; ++i){
          L.p1.qsh[l * 8 + 2*i]     = bf2f((u16)(qw[i] & 0xFFFF));
          L.p1.qsh[l * 8 + 2*i + 1] = bf2f((u16)((qw[i] >> 32) & 0xFFFF));
        }
      }
      __syncthreads();
      float qv[8];
      #pragma unroll
      for (int i = 0; i < 8; ++i) qv[i] = L.p1.qsh[l * 8 + i];
      float acc8[8] = {0.f,0.f,0.f,0.f,0.f,0.f,0.f,0.f};
      float lsum = 0.f;
      for (int t = t0 + w; t < t1; t += 8){
        uint4 v = *(const uint4*)&ph8_lds[(t - t0) * 1024 + l * 16];
        float x[8]; unpack8(v.x, v.y, x);
        float e_ = 0.f;
        #pragma unroll
        for (int i = 0; i < 8; ++i) e_ += vv[i] * ftanh(x[i] + qv[i]);
        #pragma unroll
        for (int m = 1; m < 64; m <<= 1) e_ += __shfl_xor(e_, m, 64);
        float wt = __expf(e_);          // |e| <= sum|v_att| ~ 8.2
        lsum += wt;
        float h[8]; unpack8(v.z, v.w, h);
        #pragma unroll
        for (int i = 0; i < 8; ++i) acc8[i] = fmaf(wt, h[i], acc8[i]);
      }
      *(f32x4*)&L.p1.red[w][l * 8]     = *(f32x4*)&acc8[0];
      *(f32x4*)&L.p1.red[w][l * 8 + 4] = *(f32x4*)&acc8[4];
      if (l == 0) L.p1.ls[w] = lsum;
      __syncthreads();
      if (tid < 256){
        float v0 = 0.f, v1 = 0.f;
        #pragma unroll
        for (int ww = 0; ww < 8; ++ww){
          v0 += L.p1.red[ww][tid * 2];
          v1 += L.p1.red[ww][tid * 2 + 1];
        }
        u32 pk = ((u32)f2bf(v1) << 16) | (u32)f2bf(v0);
        atomic_pk_bf16(g_.att_pk + ((size_t)p * cB + b_att) * 256 + tid, pk);
      }
      if (tid == 0){
        float ls = 0.f;
        #pragma unroll
        for (int i = 0; i < 8; ++i) ls += L.p1.ls[i];
        atomicAdd(&g_.att_l[p * cB + b_att], ls);
      }
    }
    __syncthreads();                     // drains adds (compiler waitcnt)
    if (tid == 0) sig(&ctl[AFLAG + blk], (u32)(s + 1));
    // ================= B =================================================
    if (blk < 128){
      if (tid < 64) pollge(ctl + AFLAG, 256, (u32)(s + 1));
      __syncthreads();
      stage_att(L, g_.att_pk + (size_t)p * cB * 256, g_.att_l + p * cB, tid);
      __syncthreads();
      if (tid == 0) sig(&ctl[SFLAG + p * 128 + blk], (u32)(s >> 1) + 1u);
      // optimistic tagged g0 prefetch + c0 (latency hides under gemv)
      u32 gw[4]; bool gok = true; float cpre = 0.f;
      int bb = tid >> 3, dc = tid & 7, d = blk * 8 + dc;
      if (tid < 256){
        #pragma unroll
        for (int g = 0; g < 4; ++g){
          gw[g] = ld_su(&g_.g0t[(size_t)bb * 4096 + g * 1024 + d]);
          gok &= ((gw[g] >> 16) == (u32)s);
        }
        cpre = g_.c0[(size_t)p * cB * cD + bb * cD + d];
      }
      gemv_reg<4, 4, SPA>(wB, L, tid);
      __syncthreads();
      if (tid < 256){
        while (!__all(gok)){
          gok = true;
          #pragma unroll
          for (int g = 0; g < 4; ++g){
            gw[g] = ld_su(&g_.g0t[(size_t)bb * 4096 + g * 1024 + d]);
            gok &= ((gw[g] >> 16) == (u32)s);
          }
          if (!__all(gok)) __builtin_amdgcn_s_sleep(1);
        }
        int mt = bb >> 4, rr = bb & 15;
        float gate[4];
        #pragma unroll
        for (int g = 0; g < 4; ++g){
          int jj = g * 8 + dc;
          float v = 0.f;
          #pragma unroll
          for (int kh = 0; kh < 4; ++kh)
            v += L.gv.acc[(jj >> 4) * 4 + kh][mt][rr][jj & 15];
          gate[g] = v * DS + bf2f((u16)(gw[g] & 0xFFFF));
        }
        float c = fsigm(gate[1]) * cpre + fsigm(gate[0]) * ftanh(gate[2]);
        float z = fsigm(gate[3]) * ftanh(c);
        g_.c0[(size_t)(p ^ 1) * cB * cD + bb * cD + d] = c;   // block-private
        st_scb(&g_.z0f8[bb * cD + d], f2fp8(z * 8.f));
      }
      __syncthreads();
      if (tid == 0) sig(&ctl[Z0FLAG + blk], (u32)(s + 1));
    } else {
      if (tid < 64) pollge(ctl + Z1FLAG, 128, (u32)s);   // z1(s) ready
      __syncthreads();
      stage_z(L, g_.z1f8, tid);
      __syncthreads();
      gemv_reg<4, 8, SPZ>(wB, L, tid);
      __syncthreads();
      {
        const int jb = (blk - 128) * 32;
        int bb = tid >> 4, j2 = (tid & 15) * 2;
        int mt = bb >> 4, rr = bb & 15;
        u32 ow[2];
        #pragma unroll
        for (int k = 0; k < 2; ++k){
          int jj = j2 + k;
          float v = 0.f;
          #pragma unroll
          for (int kh = 0; kh < 4; ++kh)
            v += L.gv.acc[(jj >> 4) * 4 + kh][mt][rr][jj & 15];
          ow[k] = ((u32)(s + 1) << 16) | (u32)f2bf(v * DS + g_.bias01[jb + jj]);
        }
        st_sc8(&g_.hh1t[(size_t)bb * 4096 + jb + j2], ((u64)ow[1] << 32) | ow[0]);
      }
    }
    // ================= C =================================================
    if (blk < 128){
      if (tid < 64) pollge(ctl + Z0FLAG, 128, (u32)(s + 1));
      __syncthreads();
      stage_z(L, g_.z0f8, tid);
      __syncthreads();
      // optimistic tagged hh1 prefetch + c1
      u32 hw[4]; bool hok = true; float cpre = 0.f;
      int bb = tid >> 3, dc = tid & 7, d = blk * 8 + dc;
      if (tid < 256){
        #pragma unroll
        for (int g = 0; g < 4; ++g){
          hw[g] = ld_su(&g_.hh1t[(size_t)bb * 4096 + g * 1024 + d]);
          hok &= ((hw[g] >> 16) == (u32)(s + 1));
        }
        cpre = g_.c1[(size_t)p * cB * cD + bb * cD + d];
      }
      gemv_reg<4, 8, SPZ>(wC, L, tid);
      __syncthreads();
      if (tid < 256){
        while (!__all(hok)){
          hok = true;
          #pragma unroll
          for (int g = 0; g < 4; ++g){
            hw[g] = ld_su(&g_.hh1t[(size_t)bb * 4096 + g * 1024 + d]);
            hok &= ((hw[g] >> 16) == (u32)(s + 1));
          }
          if (!__all(hok)) __builtin_amdgcn_s_sleep(1);
        }
        int mt = bb >> 4, rr = bb & 15;
        float gate[4];
        #pragma unroll
        for (int g = 0; g < 4; ++g){
          int jj = g * 8 + dc;
          float v = 0.f;
          #pragma unroll
          for (int kh = 0; kh < 4; ++kh)
            v += L.gv.acc[(jj >> 4) * 4 + kh][mt][rr][jj & 15];
          gate[g] = v * DS + bf2f((u16)(hw[g] & 0xFFFF));
        }
        float c = fsigm(gate[1]) * cpre + fsigm(gate[0]) * ftanh(gate[2]);
        float z = fsigm(gate[3]) * ftanh(c);
        g_.c1[(size_t)(p ^ 1) * cB * cD + bb * cD + d] = c;   // block-private
        g_.z1all[((size_t)s + 1) * cB * cD + bb * cD + d] = f2bf(z);
        st_scb(&g_.z1f8[bb * cD + d], f2fp8(z * 8.f));
      }
      __syncthreads();
      if (tid == 0) sig(&ctl[Z1FLAG + blk], (u32)(s + 1));
    } else if (blk < 192){
      if (tid < 64) pollge(ctl + Z0FLAG, 128, (u32)(s + 1));
      __syncthreads();
      stage_z(L, g_.z0f8, tid);
      __syncthreads();
      gemv_reg<2, 16, SPZ>(wC, L, tid);
      __syncthreads();
      if (s < cNS - 1){
        const int jb = (blk - 128) * 64;
        int bb = tid >> 4, j4 = (tid & 15) * 4;
        int mt = bb >> 4, rr = bb & 15;
        const u16* eyr = g_.eyproj + (((size_t)(s + 1) * cB + bb) * 4096) + jb + j4;
        u32 ow[4];
        #pragma unroll
        for (int k = 0; k < 4; ++k){
          int jj = j4 + k;
          float v = 0.f;
          #pragma unroll
          for (int kh = 0; kh < 2; ++kh)
            v += L.gv.acc[(jj >> 4) * 2 + kh][mt][rr][jj & 15];
          ow[k] = ((u32)(s + 1) << 16) | (u32)f2bf(v * DS + bf2f(eyr[k]));
        }
        st_sc8(&g_.g0t[(size_t)bb * 4096 + jb + j4],     ((u64)ow[1] << 32) | ow[0]);
        st_sc8(&g_.g0t[(size_t)bb * 4096 + jb + j4 + 2], ((u64)ow[3] << 32) | ow[2]);
      }
    } else if (blk < 208){
      if (tid < 64) pollge(ctl + Z0FLAG, 128, (u32)(s + 1));
      __syncthreads();
      stage_z(L, g_.z0f8, tid);
      __syncthreads();
      gemv_reg<4, 8, SPZ>(wC, L, tid);
      __syncthreads();
      if (s < cNS - 1){
        const int jb = (blk - 192) * 32;
        int bb = tid >> 4, j2 = (tid & 15) * 2;
        int mt = bb >> 4, rr = bb & 15;
        u32 ow[2];
        #pragma unroll
        for (int k = 0; k < 2; ++k){
          int jj = j2 + k;
          float v = 0.f;
          #pragma unroll
          for (int kh = 0; kh < 4; ++kh)
            v += L.gv.acc[(jj >> 4) * 4 + kh][mt][rr][jj & 15];
          ow[k] = ((u32)(s + 1) << 16) | (u32)f2bf(v * DS);
        }
        st_sc8(&g_.qt[(size_t)bb * cA + jb + j2], ((u64)ow[1] << 32) | ow[0]);
      }
    } else if (blk == 208){
      if (tid < 64) pollge(ctl + SFLAG + p * 128, 128, (u32)(s >> 1) + 1u);
      __syncthreads();
      {
        u32* aa = g_.att_pk + (size_t)p * cB * 256;
        for (int i = tid; i < cB * 256; i += 512) st_su(&aa[i], 0);
        if (tid < cB) st_sc(&g_.att_l[p * cB + tid], 0.f);
      }
      __syncthreads();
      if (tid == 0) sig(&ctl[ZDONE + p * 16], (u32)(s >> 1) + 1u);
    }
  }
}

// ------------------------------ epilogue -----------------------------------
__global__ __launch_bounds__(256) void k_ce1(const u16* __restrict__ z1all,
    const u16* __restrict__ Woutb, const float* __restrict__ bout,
    const int* __restrict__ ys, float* __restrict__ pmax, float* __restrict__ psum,
    int* __restrict__ pai, float* __restrict__ tgtl){
  int blk = blockIdx.x;
  int sc = blk / 40, vc = blk % 40;
  int tid = threadIdx.x, w = tid >> 6, l = tid & 63;
  int kin = 8 * (l >> 4), col = l & 15;
  int v0 = vc * 128 + w * 32;
  int vA = v0 + col, vB = v0 + 16 + col;
  float boA = (vA < cV) ? bout[vA] : 0.f;
  float boB = (vB < cV) ? bout[vB] : 0.f;
  const u16* wrA = Woutb + (size_t)((vA < cV) ? vA : cV - 1) * cD;
  const u16* wrB = Woutb + (size_t)((vB < cV) ? vB : cV - 1) * cD;
  __shared__ int tgt_sh[32];
  __shared__ float rsm[4][32], rss[4][32];
  __shared__ int rsi[4][32];
  for (int si = 0; si < 5; ++si){
    int s = sc * 5 + si;
    if (tid < 32) tgt_sh[tid] = (s < cL) ? ys[tid * cL + s] : EOS;
    __syncthreads();
    const u16* z1s = z1all + ((size_t)s + 1) * cB * cD;
    f32x4 aA0 = {0.f,0.f,0.f,0.f}, aA1 = {0.f,0.f,0.f,0.f};
    f32x4 aB0 = {0.f,0.f,0.f,0.f}, aB1 = {0.f,0.f,0.f,0.f};
    for (int kc = 0; kc < 32; ++kc){
      int k = kc * 32 + kin;
      s16x8 x0 = LD8(z1s + (size_t)col * cD + k);
      s16x8 x1 = LD8(z1s + (size_t)(16 + col) * cD + k);
      s16x8 bA = LD8(wrA + k);
      s16x8 bB = LD8(wrB + k);
      aA0 = MFMA(x0, bA, aA0); aA1 = MFMA(x1, bA, aA1);
      aB0 = MFMA(x0, bB, aB0); aB1 = MFMA(x1, bB, aB1);
    }
    #pragma unroll
    for (int mt = 0; mt < 2; ++mt)
    #pragma unroll
    for (int reg = 0; reg < 4; ++reg){
      int row = mt * 16 + (l >> 4) * 4 + reg;
      float va = (mt ? aA1[reg] : aA0[reg]) + boA; if (vA >= cV) va = -1e30f;
      float vb = (mt ? aB1[reg] : aB0[reg]) + boB; if (vB >= cV) vb = -1e30f;
      int tg = tgt_sh[row];
      if (vA == tg) tgtl[(size_t)s * cB + row] = va;
      if (vB == tg) tgtl[(size_t)s * cB + row] = vb;
      float mx = fmaxf(va, vb);
      int ix = (va >= vb) ? vA : vB;
      #pragma unroll
      for (int m = 1; m < 16; m <<= 1){
        float om = __shfl_xor(mx, m, 64);
        int oi = __shfl_xor(ix, m, 64);
        if (om > mx || (om == mx && oi < ix)){ mx = om; ix = oi; }
      }
      float se = __expf(va - mx) + __expf(vb - mx);
      #pragma unroll
      for (int m = 1; m < 16; m <<= 1) se += __shfl_xor(se, m, 64);
      if ((l & 15) == 0){ rsm[w][row] = mx; rss[w][row] = se; rsi[w][row] = ix; }
    }
    __syncthreads();
    if (tid < 32){
      int b = tid;
      float gm = -1e30f;
      #pragma unroll
      for (int w2 = 0; w2 < 4; ++w2) gm = fmaxf(gm, rsm[w2][b]);
      float gs = 0.f; float bv = -1e30f; int bix = 0x7fffffff;
      #pragma unroll
      for (int w2 = 0; w2 < 4; ++w2){
        gs += rss[w2][b] * __expf(rsm[w2][b] - gm);
        float v = rsm[w2][b]; int ii = rsi[w2][b];
        if (v > bv || (v == bv && ii < bix)){ bv = v; bix = ii; }
      }
      size_t o = ((size_t)s * cB + b) * 40 + vc;
      pmax[o] = gm; psum[o] = gs; pai[o] = bix;
    }
    __syncthreads();
  }
}

__global__ __launch_bounds__(64) void k_ce2(const float* __restrict__ pmax,
    const float* __restrict__ psum, const int* __restrict__ pai,
    const float* __restrict__ tgtl, const int* __restrict__ ys,
    float* __restrict__ cestep){
  int s = blockIdx.x, tid = threadIdx.x;
  float nll = 0.f, cor = 0.f;
  if (tid < 32){
    int b = tid;
    size_t o = ((size_t)s * cB + b) * 40;
    float gm = -1e30f;
    for (int c = 0; c < 40; ++c) gm = fmaxf(gm, pmax[o + c]);
    float gs = 0.f; float bv = -1e30f; int bix = 0x7fffffff;
    for (int c = 0; c < 40; ++c){
      gs += psum[o + c] * __expf(pmax[o + c] - gm);
      float v = pmax[o + c]; int ii = pai[o + c];
      if (v > bv || (v == bv && ii < bix)){ bv = v; bix = ii; }
    }
    nll = __logf(gs) + gm - tgtl[(size_t)s * cB + b];
    int tgt = (s < cL) ? ys[b * cL + s] : EOS;
    cor = (bix == tgt) ? 1.f : 0.f;
  }
  #pragma unroll
  for (int m = 1; m < 64; m <<= 1){
    nll += __shfl_xor(nll, m, 64); cor += __shfl_xor(cor, m, 64);
  }
  if (tid == 0){ cestep[s * 2] = nll; cestep[s * 2 + 1] = cor; }
}

__global__ __launch_bounds__(256) void k_ce3(const float* __restrict__ cestep,
                                             float* __restrict__ out){
  int tid = threadIdx.x;
  float nll = 0.f, cor = 0.f;
  for (int s = tid; s < cNS; s += 256){ nll += cestep[s * 2]; cor += cestep[s * 2 + 1]; }
  __shared__ float sn[4], sc_[4];
  int w = tid >> 6, l = tid & 63;
  #pragma unroll
  for (int m = 1; m < 64; m <<= 1){
    nll += __shfl_xor(nll, m, 64); cor += __shfl_xor(cor, m, 64);
  }
  if (l == 0){ sn[w] = nll; sc_[w] = cor; }
  __syncthreads();
  if (tid == 0){
    float a = sn[0] + sn[1] + sn[2] + sn[3];
    float b = sc_[0] + sc_[1] + sc_[2] + sc_[3];
    out[0] = a / (float)(cB * cNS) * (float)cL;
    out[1] = b / (float)(cB * cNS);
  }
}

// ------------------------------- host --------------------------------------
extern "C" void kernel_launch(void* const* d_in, const int* in_sizes, int n_in,
                              void* d_out, int out_size, void* d_ws, size_t ws_size,
                              hipStream_t stream){
  const float* hpad = (const float*)d_in[0];
  const int*   hlen = (const int*)d_in[1];
  const int*   ys   = (const int*)d_in[2];
  const float* embed= (const float*)d_in[3];
  const float* Wout = (const float*)d_in[4];
  const float* bout = (const float*)d_in[5];
  const float* Wenc = (const float*)d_in[6];
  const float* Wdec = (const float*)d_in[7];
  const float* vatt = (const float*)d_in[8];
  const float* Wih0 = (const float*)d_in[9];
  const float* bih0 = (const float*)d_in[10];
  const float* Whh0 = (const float*)d_in[11];
  const float* bhh0 = (const float*)d_in[12];
  const float* Wih1 = (const float*)d_in[13];
  const float* bih1 = (const float*)d_in[14];
  const float* Whh1 = (const float*)d_in[15];
  const float* bhh1 = (const float*)d_in[16];
  (void)in_sizes; (void)n_in; (void)out_size; (void)ws_size;

  char* base = (char*)d_ws;
  size_t off = 0;
  auto alloc = [&](size_t bytes) -> void* {
    void* r = base + off; off += (bytes + 255) & ~(size_t)255; return r;
  };
  u32*   ctl     = (u32*)  alloc(1024 * 4);
  u16*   hpadM   = (u16*)  alloc((size_t)cB * cT * cE * 2);
  u8*    ph8     = (u8*)   alloc((size_t)cB * cT * 1024);
  u16*   embb    = (u16*)  alloc((size_t)cV * cD * 2);
  u16*   ey      = (u16*)  alloc((size_t)cNS * cB * cD * 2);
  u16*   eyproj  = (u16*)  alloc((size_t)cNS * cB * 4096 * 2);
  u16*   z1all   = (u16*)  alloc((size_t)(cNS + 1) * cB * cD * 2);
  u16*   WencT   = (u16*)  alloc((size_t)cA * cE * 2);
  u16*   Wih0m   = (u16*)  alloc((size_t)4096 * cD * 2);
  u16*   Woutb   = (u16*)  alloc((size_t)cV * cD * 2);
  u8*    Wapf8   = (u8*)   alloc((size_t)4096 * 512);
  u8*    Wih1f8  = (u8*)   alloc((size_t)4096 * 1024);
  u8*    Whh1f8  = (u8*)   alloc((size_t)4096 * 1024);
  u8*    Whh0f8  = (u8*)   alloc((size_t)4096 * 1024);
  u8*    WdecTf8 = (u8*)   alloc((size_t)512 * 1024);
  float* bias01  = (float*)alloc(4096 * 4);
  u32*   qt      = (u32*)  alloc((size_t)cB * cA * 4);
  u32*   att_pk  = (u32*)  alloc((size_t)2 * cB * 256 * 4);
  float* att_l   = (float*)alloc((size_t)2 * cB * 4);
  u32*   g0t     = (u32*)  alloc((size_t)cB * 4096 * 4);
  u32*   hh1t    = (u32*)  alloc((size_t)cB * 4096 * 4);
  u8*    z0f8    = (u8*)   alloc((size_t)cB * cD);
  u8*    z1f8    = (u8*)   alloc((size_t)cB * cD);
  float* c0      = (float*)alloc((size_t)2 * cB * cD * 4);
  float* c1      = (float*)alloc((size_t)2 * cB * cD * 4);
  float* pmax    = (float*)alloc((size_t)cNS * cB * 40 * 4);
  float* psum    = (float*)alloc((size_t)cNS * cB * 40 * 4);
  int*   pai     = (int*)  alloc((size_t)cNS * cB * 40 * 4);
  float* tgtl    = (float*)alloc((size_t)cNS * cB * 4);
  float* cestep  = (float*)alloc((size_t)cNS * 2 * 4);

  k_init<<<64, 256, 0, stream>>>(ctl, qt, c0, c1, z1f8, att_pk, att_l, hh1t);
  k_cvt<<<2048, 256, 0, stream>>>(hpad, hpadM, cB * cT * cE / 4);
  k_cvt8I<<<1024, 256, 0, stream>>>(hpad, ph8, cB * cT * 64);
  k_cvt<<<2048, 256, 0, stream>>>(embed, embb, cV * cD / 4);
  k_cvt<<<2048, 256, 0, stream>>>(Wout, Woutb, cV * cD / 4);
  k_slice<<<1024, 256, 0, stream>>>(Wih0, Wih0m, 4096 * cD, 10, 1536, 0);
  k_transp<<<256, 256, 0, stream>>>(Wenc, WencT, cA * cE, 9, cA);
  k_bias<<<16, 256, 0, stream>>>(bih1, bhh1, bias01, 4096);
  k_wf8perm<<<512, 256, 0, stream>>>(Wih0, Wapf8, 4096 * 512 / 4, 9, 1536, 1024);
  k_wf8perm<<<1024, 256, 0, stream>>>(Wih1, Wih1f8, 4096 * 1024 / 4, 10, 1024, 0);
  k_wf8<<<1024, 256, 0, stream>>>(Whh1, Whh1f8, 4096 * 1024 / 4);
  k_wf8<<<1024, 256, 0, stream>>>(Whh0, Whh0f8, 4096 * 1024 / 4);
  k_wf8t<<<128, 256, 0, stream>>>(Wdec, WdecTf8, 512 * 1024 / 4);
  k_gather<<<1200, 256, 0, stream>>>(embb, ys, ey, cNS * cB * 128);
  k_pe2<<<200, 512, 0, stream>>>(hpadM, WencT, ph8);
  k_ey2<<<dim3(38, 8), 512, 0, stream>>>(ey, Wih0m, bih0, bhh0, eyproj, g0t);

  LoopArgs la;
  la.hlen = hlen; la.ph8 = ph8; la.eyproj = eyproj;
  la.Wapf8 = Wapf8; la.Whh1f8 = Whh1f8; la.Wih1f8 = Wih1f8;
  la.Whh0f8 = Whh0f8; la.WdecTf8 = WdecTf8;
  la.vatt = vatt; la.bias01 = bias01;
  la.qt = qt; la.att_pk = att_pk; la.att_l = att_l;
  la.g0t = g0t; la.hh1t = hh1t; la.z0f8 = z0f8; la.z1f8 = z1f8;
  la.c0 = c0; la.c1 = c1; la.z1all = z1all; la.ctl = ctl;
  k_loop<<<NBLK, 512, 0, stream>>>(la);

  k_ce1<<<1200, 256, 0, stream>>>(z1all, Woutb, bout, ys, pmax, psum, pai, tgtl);
  k_ce2<<<cNS, 64, 0, stream>>>(pmax, psum, pai, tgtl, ys, cestep);
  k_ce3<<<1, 256, 0, stream>>>(cestep, (float*)d_out);
}